// Round 19
// baseline (74.864 us; speedup 1.0000x reference)
//
#include <hip/hip_runtime.h>
#include <stdint.h>

typedef unsigned long long u64;

#define NMS_T 0.7f
#define MINSZ 16.0f
#define NPRE 6000
#define NPOST 300
#define CA   384
#define NG   6          // groups of 64 = CA/64
#define CAPA 2048
#define CAP6 8192
#define NBIN 2048
#define NSLOT 32
#define GRIDC 128
#define GRIDR 9         // NG*CA/256

// ---- workspace layout (bytes) ----
#define OFF_CAND6  0                          // CAP6*8 (fallback only)
#define OFF_CANDA  (OFF_CAND6 + CAP6*8)       // CAPA*8
#define OFF_ORDER6 (OFF_CANDA + CAPA*8)       // NPRE*4  (fallback)
#define OFF_ROI6   (OFF_ORDER6 + NPRE*4)      // NPRE*16 (fallback)
#define OFF_GMAT   (OFF_ROI6 + NPRE*16)       // NG*CA*8 transposed gmatT[gr*CA+col]
#define OFF_SLOT   (OFF_GMAT + NG*CA*8)       // NSLOT*NBIN*4
#define OFF_CNT    (OFF_SLOT + NSLOT*NBIN*4)  // 32: [2]=done1 [3]=galloc [6]=done2

__device__ __forceinline__ unsigned inv_key(float s) {
    unsigned u = __float_as_uint(s);
    unsigned k = (u & 0x80000000u) ? ~u : (u | 0x80000000u);
    return ~k;   // ascending inv == descending score
}

__device__ __forceinline__ float4 decode_box(const float4 a, const float4 l,
                                             float ih, float iw) {
    float h  = a.z - a.x;
    float w  = a.w - a.y;
    float cy = a.x + 0.5f * h;
    float cx = a.y + 0.5f * w;
    float ncy = l.x * h + cy;
    float ncx = l.y * w + cx;
    float nh  = expf(l.z) * h;
    float nw  = expf(l.w) * w;
    float y1 = fminf(fmaxf(ncy - 0.5f * nh, 0.0f), ih);
    float x1 = fminf(fmaxf(ncx - 0.5f * nw, 0.0f), iw);
    float y2 = fminf(fmaxf(ncy + 0.5f * nh, 0.0f), ih);
    float x2 = fminf(fmaxf(ncx + 0.5f * nw, 0.0f), iw);
    return make_float4(y1, x1, y2, x2);
}

__device__ __forceinline__ int sbin_of(float s) {
    int b = (int)(s * 2048.0f);
    b = b < 0 ? 0 : (b > 2047 ? 2047 : b);
    return 2047 - b;           // ascending = descending score
}

// fast block scan of 2048-bin histogram (2 barriers): bins containing ranks t0/t1
__device__ void fastscan2048(const unsigned* __restrict__ h, unsigned t0, unsigned t1,
                             unsigned* swave, unsigned* res) {
    int t = threadIdx.x;
    unsigned vals[8], s = 0;
#pragma unroll
    for (int j = 0; j < 8; ++j) { vals[j] = h[t * 8 + j]; s += vals[j]; }
    unsigned inc = s;
#pragma unroll
    for (int off = 1; off < 64; off <<= 1) {
        unsigned o = (unsigned)__shfl_up((int)inc, off, 64);
        if ((t & 63) >= off) inc += o;
    }
    if ((t & 63) == 63) swave[t >> 6] = inc;
    __syncthreads();
    unsigned wbase = 0;
    for (int w = 0; w < (t >> 6); ++w) wbase += swave[w];
    unsigned run = wbase + inc - s;
#pragma unroll
    for (int j = 0; j < 8; ++j) {
        unsigned c = vals[j];
        if (run < t0 && run + c >= t0) { res[0] = t * 8 + j; res[1] = run; }
        if (t1 && run < t1 && run + c >= t1) { res[2] = t * 8 + j; res[3] = run; }
        run += c;
    }
    __syncthreads();
}

// ---- 1: score-only histogram; 8x float4 register-batched loads ----
__global__ void __launch_bounds__(256) k_hist(const float* __restrict__ score, int n,
                                              unsigned* __restrict__ slots,
                                              unsigned* __restrict__ cnts) {
    __shared__ unsigned lh[NBIN];
    for (int b = threadIdx.x; b < NBIN; b += 256) lh[b] = 0;
    if (blockIdx.x == 0 && threadIdx.x < 8) cnts[threadIdx.x] = 0;
    __syncthreads();
    int gtid = blockIdx.x * 256 + threadIdx.x;
    int T = gridDim.x * 256;
    int n4 = n >> 2;
    const float4* s4 = (const float4*)score;
    for (int idx0 = gtid; idx0 < n4; idx0 += T * 8) {
        float4 v[8]; int ok[8];
#pragma unroll
        for (int k = 0; k < 8; ++k) {
            int idx = idx0 + k * T;
            ok[k] = idx < n4;
            v[k] = ok[k] ? s4[idx] : make_float4(0.f, 0.f, 0.f, 0.f);
        }
#pragma unroll
        for (int k = 0; k < 8; ++k) if (ok[k]) {
            atomicAdd(&lh[sbin_of(v[k].x)], 1u);
            atomicAdd(&lh[sbin_of(v[k].y)], 1u);
            atomicAdd(&lh[sbin_of(v[k].z)], 1u);
            atomicAdd(&lh[sbin_of(v[k].w)], 1u);
        }
    }
    for (int i = (n4 << 2) + gtid; i < n; i += T) atomicAdd(&lh[sbin_of(score[i])], 1u);
    __syncthreads();
    for (int b = threadIdx.x; b < NBIN; b += 256)
        slots[blockIdx.x * NBIN + b] = lh[b];
}

struct SmC {
    u64 skey[CAPA];          // 16 KB
    unsigned shist[NBIN];    // 8 KB
    unsigned sprefix[NBIN];  // 8 KB
};
struct SmFb {
    u64   lk[CAP6];          // 64 KB
    float y1[NPOST], x1[NPOST], y2[NPOST], x2[NPOST], ar[NPOST];
};
union SmM {
    unsigned hsum[NBIN];     // threshold prologue
    u64 win[CAPA];           // collect buffer
    SmC c;                   // rank phase
    SmFb fb;                 // fallback
};

// ---- 2: merged collect -> (last 9 arrivers) rank/matrix -> (last) scan/output ----
__global__ void __launch_bounds__(256) k_merged(
        const float4* __restrict__ loc, const float* __restrict__ score,
        const float4* __restrict__ anchor, const int* __restrict__ ph,
        const int* __restrict__ pw, int n, const unsigned* __restrict__ slots,
        u64* __restrict__ candA, u64* __restrict__ cand6,
        unsigned* __restrict__ cnts, u64* __restrict__ gmatT,
        unsigned* __restrict__ order6, float4* __restrict__ roi6,
        float* __restrict__ out) {
    __shared__ SmM sm;
    __shared__ unsigned swave[8], res[8];
    __shared__ unsigned sNW, sBase, sInvLo, sD;
    __shared__ int sIsLast;
    __shared__ float4 sroi[CA];
    __shared__ float  sarea[CA];
    __shared__ unsigned svalid[CA / 32];
    __shared__ u64 skm[NG];
    __shared__ int snk, sflag;

    const int tid = threadIdx.x, bid = blockIdx.x;
    const int gtid = bid * 256 + tid;
    const int T = GRIDC * 256;
    const float ih = (float)ph[0], iw = (float)pw[0];
    const int n4 = n >> 2, ntail = n4 << 2;
    const float4* s4 = (const float4*)score;

    // ---- thresholds from slot histogram (every block; deterministic) ----
    for (int b = tid; b < NBIN; b += 256) {
        unsigned s = 0;
#pragma unroll 4
        for (int sl = 0; sl < NSLOT; ++sl) s += slots[sl * NBIN + b];
        sm.hsum[b] = s;
    }
    __syncthreads();
    fastscan2048(sm.hsum, CA, NPRE, swave, res);
    const unsigned bA = res[0], b6 = res[2];
    const unsigned cntA_total = res[1] + sm.hsum[bA];
    const unsigned cnt6_total = res[3] + sm.hsum[b6];
    const bool mainValid = (cntA_total <= CAPA);
    if (tid == 0) sNW = 0;
    __syncthreads();                    // hsum dead (union reuse as win)

    // ---- single-pass collect of winners (hb <= bA) ----
    if (mainValid) {
        for (int idx0 = gtid; idx0 < n4; idx0 += T * 8) {
            float4 v[8]; int ok[8];
#pragma unroll
            for (int k = 0; k < 8; ++k) {
                int idx = idx0 + k * T;
                ok[k] = idx < n4;
                v[k] = ok[k] ? s4[idx] : make_float4(0.f, 0.f, 0.f, 0.f);
            }
#pragma unroll
            for (int k = 0; k < 8; ++k) if (ok[k]) {
                float sc[4] = {v[k].x, v[k].y, v[k].z, v[k].w};
                int ib = (idx0 + k * T) << 2;
#pragma unroll
                for (int c = 0; c < 4; ++c) {
                    if ((unsigned)sbin_of(sc[c]) <= bA) {
                        int i = ib + c;
                        float4 r = decode_box(anchor[i], loc[i], ih, iw);
                        bool valid = ((r.z - r.x) >= MINSZ) && ((r.w - r.y) >= MINSZ);
                        float ms = valid ? sc[c] : -__builtin_inff();
                        u64 key = ((u64)inv_key(ms) << 32) | (unsigned)i;
                        unsigned p = atomicAdd(&sNW, 1u);
                        if (p < CAPA) sm.win[p] = key;
                    }
                }
            }
        }
        for (int i = ntail + gtid; i < n; i += T) {
            float s = score[i];
            if ((unsigned)sbin_of(s) <= bA) {
                float4 r = decode_box(anchor[i], loc[i], ih, iw);
                bool valid = ((r.z - r.x) >= MINSZ) && ((r.w - r.y) >= MINSZ);
                float ms = valid ? s : -__builtin_inff();
                u64 key = ((u64)inv_key(ms) << 32) | (unsigned)i;
                unsigned p = atomicAdd(&sNW, 1u);
                if (p < CAPA) sm.win[p] = key;
            }
        }
        __syncthreads();
        unsigned NW = sNW;
        if (tid == 0 && NW) sBase = atomicAdd(&cnts[3], NW);
        __syncthreads();
        if (NW) {
            unsigned base = sBase;
            for (unsigned i = tid; i < NW; i += 256) candA[base + i] = sm.win[i];
        }
    }
    // arrive-only; last GRIDR arrivers continue as phase-C roles 0..GRIDR-1
    __threadfence();
    __syncthreads();
    if (tid == 0) sD = atomicAdd(&cnts[2], 1u);
    __syncthreads();
    unsigned d = sD;
    if (d < (unsigned)(GRIDC - GRIDR)) return;
    int role = (int)(d - (GRIDC - GRIDR));        // 0..GRIDR-1
    if (d < (unsigned)(GRIDC - 1)) {
        // <=8 pollers, short straggler wait (agent-scope loads)
        if (tid == 0) {
            while (__hip_atomic_load(&cnts[2], __ATOMIC_ACQUIRE, __HIP_MEMORY_SCOPE_AGENT) < (unsigned)GRIDC)
                __builtin_amdgcn_s_sleep(2);
        }
        __syncthreads();
    }
    __threadfence();   // acquire: all candA writes visible

    // ================= phase C: counting-sort rank -> decode -> matrix slice =================
    unsigned MA = mainValid ? cntA_total : 0;
    if (mainValid) {
        if (tid == 0) sInvLo = 0xFFFFFFFFu;
        for (int b = tid; b < NBIN; b += 256) sm.c.shist[b] = 0;
        for (int r = tid; r < CA; r += 256) { sroi[r] = make_float4(0.f,0.f,0.f,0.f); sarea[r] = 0.f; }
        if (tid < CA / 32) svalid[tid] = 0;
        u64 kreg[8];
#pragma unroll
        for (int k = 0; k < 8; ++k) {
            unsigned i = tid + k * 256u;
            kreg[k] = (i < MA) ? candA[i] : ~0ULL;
        }
        unsigned mymin = 0xFFFFFFFFu;
#pragma unroll
        for (int k = 0; k < 8; ++k) {
            unsigned hi = (unsigned)(kreg[k] >> 32);
            mymin = mymin < hi ? mymin : hi;
        }
#pragma unroll
        for (int off = 32; off; off >>= 1) {
            unsigned o = (unsigned)__shfl_down((int)mymin, off, 64);
            mymin = mymin < o ? mymin : o;
        }
        if ((tid & 63) == 0) atomicMin(&sInvLo, mymin);
        __syncthreads();
        unsigned invLo = sInvLo;
#pragma unroll
        for (int k = 0; k < 8; ++k) {
            unsigned i = tid + k * 256u;
            if (i < MA) {
                unsigned dd = ((unsigned)(kreg[k] >> 32) - invLo) >> 3;
                atomicAdd(&sm.c.shist[dd > 2047u ? 2047u : dd], 1u);
            }
        }
        __syncthreads();
        {   // fast exclusive prefix into sprefix
            unsigned vals[8], s = 0;
#pragma unroll
            for (int j = 0; j < 8; ++j) { vals[j] = sm.c.shist[tid * 8 + j]; s += vals[j]; }
            unsigned inc = s;
#pragma unroll
            for (int off = 1; off < 64; off <<= 1) {
                unsigned o = (unsigned)__shfl_up((int)inc, off, 64);
                if ((tid & 63) >= off) inc += o;
            }
            if ((tid & 63) == 63) swave[tid >> 6] = inc;
            __syncthreads();
            unsigned wbase = 0;
            for (int w = 0; w < (tid >> 6); ++w) wbase += swave[w];
            unsigned run = wbase + inc - s;
#pragma unroll
            for (int j = 0; j < 8; ++j) { sm.c.sprefix[tid * 8 + j] = run; run += vals[j]; }
        }
        __syncthreads();
#pragma unroll
        for (int k = 0; k < 8; ++k) {
            unsigned i = tid + k * 256u;
            if (i < MA) {
                unsigned dd = ((unsigned)(kreg[k] >> 32) - invLo) >> 3;
                dd = dd > 2047u ? 2047u : dd;
                unsigned pos = atomicAdd(&sm.c.sprefix[dd], 1u);
                sm.c.skey[pos] = kreg[k];
            }
        }
        __syncthreads();
#pragma unroll
        for (int k = 0; k < 8; ++k) {
            unsigned p = tid + k * 256u;
            if (p < MA) {
                u64 key = sm.c.skey[p];
                unsigned dd = ((unsigned)(key >> 32) - invLo) >> 3;
                dd = dd > 2047u ? 2047u : dd;
                unsigned e = sm.c.sprefix[dd];
                unsigned s0 = e - sm.c.shist[dd];
                int rank = (int)s0;
                for (unsigned q = s0; q < e; ++q) rank += (sm.c.skey[q] < key) ? 1 : 0;
                if (rank < CA) {
                    unsigned idx = (unsigned)key;
                    float4 b = decode_box(anchor[idx], loc[idx], ih, iw);
                    sroi[rank] = b;
                    sarea[rank] = (b.z - b.x) * (b.w - b.y);
                    if (((b.z - b.x) >= MINSZ) && ((b.w - b.y) >= MINSZ))
                        atomicOr(&svalid[rank >> 5], 1u << (rank & 31));
                }
            }
        }
        __syncthreads();
        // transposed matrix slice for this role
        {
            int task = role * 256 + tid;
            int gr = task / CA;
            int jcol = task - gr * CA;
            int j0 = gr << 6;
            u64 bits = 0;
            if (j0 < jcol) {
                float4 b = sroi[jcol];
                float ab = sarea[jcol];
                int cmax = jcol - j0; cmax = cmax > 64 ? 64 : cmax;
                for (int c = 0; c < cmax; ++c) {
                    int row = j0 + c;
                    float4 r = sroi[row];
                    float yy1 = fmaxf(r.x, b.x);
                    float xx1 = fmaxf(r.y, b.y);
                    float yy2 = fminf(r.z, b.z);
                    float xx2 = fminf(r.w, b.w);
                    float inter = fmaxf(yy2 - yy1, 0.0f) * fmaxf(xx2 - xx1, 0.0f);
                    float iou = inter / (sarea[row] + ab - inter);  // ref op order
                    if (iou > NMS_T) bits |= (1ULL << c);
                }
            }
            gmatT[gr * CA + jcol] = bits;
        }
    }
    // arrive-only done2; last continues alone
    __threadfence();
    __syncthreads();
    if (tid == 0) {
        unsigned d2 = atomicAdd(&cnts[6], 1u);
        sIsLast = (d2 == GRIDR - 1);
    }
    __syncthreads();
    if (!sIsLast) return;
    __threadfence();   // acquire

    // ================= ballot scan =================
    int Ceff = (int)(cntA_total < (unsigned)CA ? cntA_total : (unsigned)CA);
    if (tid < 64 && mainValid) {
        u64 supfut[NG], W[NG], nxtW[NG], kmask[NG];
#pragma unroll
        for (int w = 0; w < NG; ++w) {
            supfut[w] = ~(((u64)svalid[2 * w + 1] << 32) | (u64)svalid[2 * w]);
            kmask[w] = 0ull;
        }
#pragma unroll
        for (int gq = 0; gq < NG; ++gq) W[gq] = gmatT[0 * CA + 64 * gq + tid];
        int nk = 0;
        bool done = false;
#pragma unroll
        for (int g = 0; g < NG; ++g) {
            if (g < NG - 1) {
#pragma unroll
                for (int gq = 0; gq < NG; ++gq) nxtW[gq] = gmatT[(g + 1) * CA + 64 * gq + tid];
            }
            int base = 64 * g;
            if (!done && base < Ceff) {
                u64 bound = (Ceff - base >= 64) ? ~0ull : ((1ull << (Ceff - base)) - 1ull);
                u64 live = ~supfut[g] & bound;
                u64 km = 0;
                while (live) {
                    int b = (int)__builtin_ctzll(live);
                    km |= 1ull << b;
                    ++nk;
                    if (nk == NPOST) { done = true; break; }
                    bool s = (W[g] >> b) & 1ull;
                    u64 supm = __ballot(s);
                    live &= ~(supm | (1ull << b));
                }
                kmask[g] = km;
                if (!done && g < NG - 1) {
#pragma unroll
                    for (int gq = 0; gq < NG; ++gq) {
                        if (gq > g) {
                            bool any = (W[gq] & km) != 0ull;
                            supfut[gq] |= __ballot(any);
                        }
                    }
                }
            }
#pragma unroll
            for (int gq = 0; gq < NG; ++gq) W[gq] = nxtW[gq];
        }
        if (tid == 0) {
            snk = nk;
            sflag = (nk < NPOST && cnt6_total > (unsigned)Ceff) ? 1 : 0;
#pragma unroll
            for (int g = 0; g < NG; ++g) skm[g] = kmask[g];
        }
    }
    if (tid == 0 && !mainValid) {
        snk = 0; sflag = 1;
#pragma unroll
        for (int g = 0; g < NG; ++g) skm[g] = 0ull;
    }
    __syncthreads();
    int nk = snk, flag = sflag;
    float4* out4 = (float4*)out;
    if (!flag) {
        int basepc[NG];
        {
            int run = 0;
#pragma unroll
            for (int g = 0; g < NG; ++g) { basepc[g] = run; run += __popcll(skm[g]); }
        }
        int wv = tid >> 6, j = tid & 63;
#pragma unroll
        for (int gg = 0; gg < 2; ++gg) {
            int g = wv + 4 * gg;
            if (g < NG) {
                u64 km = skm[g];
                if ((km >> j) & 1ull) {
                    int rank = basepc[g] + __popcll(km & ((1ull << j) - 1ull));
                    if (rank < NPOST) out4[rank] = sroi[64 * g + j];
                }
            }
        }
        for (int k = nk + tid; k < NPOST; k += 256) out4[k] = make_float4(0.f,0.f,0.f,0.f);
        return;
    }
    // ---------- exact fallback (gated; never taken on sane data) ----------
    __syncthreads();
    if (tid == 0) sNW = 0;
    __syncthreads();
    for (int i = tid; i < n; i += 256) {
        float s = score[i];
        if ((unsigned)sbin_of(s) <= b6) {
            float4 r = decode_box(anchor[i], loc[i], ih, iw);
            bool valid = ((r.z - r.x) >= MINSZ) && ((r.w - r.y) >= MINSZ);
            float ms = valid ? s : -__builtin_inff();
            u64 key = ((u64)inv_key(ms) << 32) | (unsigned)i;
            unsigned p = atomicAdd(&sNW, 1u);
            if (p < CAP6) cand6[p] = key;
        }
    }
    __threadfence();
    __syncthreads();
    unsigned M = sNW < (unsigned)CAP6 ? sNW : (unsigned)CAP6;
    for (unsigned i = tid; i < CAP6; i += 256) sm.fb.lk[i] = (i < M) ? cand6[i] : ~0ULL;
    for (int r = tid; r < NPRE; r += 256) order6[r] = 0xFFFFFFFFu;
    __syncthreads();
    for (unsigned c = tid; c < M; c += 256) {
        u64 key = sm.fb.lk[c];
        int rank = 0;
        for (unsigned j = 0; j < M; ++j) rank += (sm.fb.lk[j] < key) ? 1 : 0;
        if (rank < NPRE) order6[rank] = (unsigned)key;
    }
    __syncthreads();
    for (int r = tid; r < NPRE; r += 256) {
        unsigned idx = order6[r];
        float4 b = make_float4(0.f, 0.f, 0.f, 0.f);
        if (idx < (unsigned)n) b = decode_box(anchor[idx], loc[idx], ih, iw);
        roi6[r] = b;
    }
    __syncthreads();
    if (tid < 64) {
        int lane = tid;
        int nk2 = 0;
        for (int i = 0; i < NPRE; i++) {
            float4 b = roi6[i];
            float hs = b.z - b.x, wd = b.w - b.y;
            if (!(hs >= MINSZ && wd >= MINSZ)) continue;
            float ab = hs * wd;
            bool sup = false;
            for (int base = 0; base < nk2 && !sup; base += 64) {
                int t = base + lane;
                bool s = false;
                if (t < nk2) {
                    float yy1 = fmaxf(b.x, sm.fb.y1[t]);
                    float xx1 = fmaxf(b.y, sm.fb.x1[t]);
                    float yy2 = fminf(b.z, sm.fb.y2[t]);
                    float xx2 = fminf(b.w, sm.fb.x2[t]);
                    float inter = fmaxf(yy2 - yy1, 0.0f) * fmaxf(xx2 - xx1, 0.0f);
                    float iou = inter / (sm.fb.ar[t] + ab - inter);
                    s = iou > NMS_T;
                }
                sup = (__ballot(s) != 0ULL);
            }
            if (!sup) {
                if (lane == 0) {
                    sm.fb.y1[nk2] = b.x; sm.fb.x1[nk2] = b.y;
                    sm.fb.y2[nk2] = b.z; sm.fb.x2[nk2] = b.w; sm.fb.ar[nk2] = ab;
                }
                nk2++;
                if (nk2 == NPOST) break;
            }
        }
        for (int k = lane; k < NPOST; k += 64) {
            float4 o = make_float4(0.f, 0.f, 0.f, 0.f);
            if (k < nk2) o = make_float4(sm.fb.y1[k], sm.fb.x1[k], sm.fb.y2[k], sm.fb.x2[k]);
            out4[k] = o;
        }
    }
}

extern "C" void kernel_launch(void* const* d_in, const int* in_sizes, int n_in,
                              void* d_out, int out_size, void* d_ws, size_t ws_size,
                              hipStream_t stream) {
    const float4* loc    = (const float4*)d_in[0];
    const float*  score  = (const float*)d_in[1];
    const float4* anchor = (const float4*)d_in[2];
    const int*    ph     = (const int*)d_in[3];
    const int*    pw     = (const int*)d_in[4];
    int n = in_sizes[1];

    char* ws = (char*)d_ws;
    u64*      cand6  = (u64*)(ws + OFF_CAND6);
    u64*      candA  = (u64*)(ws + OFF_CANDA);
    unsigned* order6 = (unsigned*)(ws + OFF_ORDER6);
    float4*   roi6   = (float4*)(ws + OFF_ROI6);
    u64*      gmatT  = (u64*)(ws + OFF_GMAT);
    unsigned* slots  = (unsigned*)(ws + OFF_SLOT);
    unsigned* cnts   = (unsigned*)(ws + OFF_CNT);
    float* out = (float*)d_out;

    k_hist   <<<dim3(NSLOT), dim3(256), 0, stream>>>(score, n, slots, cnts);
    k_merged <<<dim3(GRIDC), dim3(256), 0, stream>>>(loc, score, anchor, ph, pw, n, slots,
                                                     candA, cand6, cnts, gmatT,
                                                     order6, roi6, out);
}

// Round 20
// 54.364 us; speedup vs baseline: 1.3771x; 1.3771x over previous
//
#include <hip/hip_runtime.h>
#include <stdint.h>

typedef unsigned long long u64;

#define NMS_T 0.7f
#define MINSZ 16.0f
#define NPRE 6000
#define NPOST 300
#define CA   384
#define NG   6          // groups of 64 = CA/64
#define CAP6 8192
#define NBIN 2048
#define GRIDC 128
#define GRIDR 9         // NG*CA/256
#define KCAP 32         // winner slots per collect block
#define MT   (GRIDC*KCAP)   // 4096 candidate slots (sentinel-padded)
#define TFIX 0.9990234375f  // 1 - 1024/2^20; E[winners]=1024 on U[0,1)

// ---- workspace layout (bytes) ----
#define OFF_CAND6  0                          // CAP6*8 (fallback only)
#define OFF_CANDA  (OFF_CAND6 + CAP6*8)       // MT*8 = 32768
#define OFF_CANDW  (OFF_CANDA + MT*8)         // GRIDC*4 (written every call)
#define OFF_VW     (OFF_CANDW + GRIDC*4)      // GRIDC*4 (written every call)
#define OFF_ORDER6 (OFF_VW + GRIDC*4)         // NPRE*4  (fallback)
#define OFF_ROI6   (OFF_ORDER6 + NPRE*4)      // NPRE*16 (fallback)
#define OFF_GMAT   (OFF_ROI6 + NPRE*16)       // NG*CA*8 transposed gmatT[gr*CA+col]
#define OFF_CNT    (OFF_GMAT + NG*CA*8)       // 32: [6]=done2 (zeroed by k_collect blk0)

__device__ __forceinline__ unsigned inv_key(float s) {
    unsigned u = __float_as_uint(s);
    unsigned k = (u & 0x80000000u) ? ~u : (u | 0x80000000u);
    return ~k;   // ascending inv == descending score
}

__device__ __forceinline__ float4 decode_box(const float4 a, const float4 l,
                                             float ih, float iw) {
    float h  = a.z - a.x;
    float w  = a.w - a.y;
    float cy = a.x + 0.5f * h;
    float cx = a.y + 0.5f * w;
    float ncy = l.x * h + cy;
    float ncx = l.y * w + cx;
    float nh  = expf(l.z) * h;
    float nw  = expf(l.w) * w;
    float y1 = fminf(fmaxf(ncy - 0.5f * nh, 0.0f), ih);
    float x1 = fminf(fmaxf(ncx - 0.5f * nw, 0.0f), iw);
    float y2 = fminf(fmaxf(ncy + 0.5f * nh, 0.0f), ih);
    float x2 = fminf(fmaxf(ncx + 0.5f * nw, 0.0f), iw);
    return make_float4(y1, x1, y2, x2);
}

__device__ __forceinline__ int sbin_of(float s) {
    int b = (int)(s * 2048.0f);
    b = b < 0 ? 0 : (b > 2047 ? 2047 : b);
    return 2047 - b;           // ascending = descending score
}

// fast block scan of 2048-bin histogram (2 barriers): bins containing ranks t0/t1
__device__ void fastscan2048(const unsigned* __restrict__ h, unsigned t0, unsigned t1,
                             unsigned* swave, unsigned* res) {
    int t = threadIdx.x;
    unsigned vals[8], s = 0;
#pragma unroll
    for (int j = 0; j < 8; ++j) { vals[j] = h[t * 8 + j]; s += vals[j]; }
    unsigned inc = s;
#pragma unroll
    for (int off = 1; off < 64; off <<= 1) {
        unsigned o = (unsigned)__shfl_up((int)inc, off, 64);
        if ((t & 63) >= off) inc += o;
    }
    if ((t & 63) == 63) swave[t >> 6] = inc;
    __syncthreads();
    unsigned wbase = 0;
    for (int w = 0; w < (t >> 6); ++w) wbase += swave[w];
    unsigned run = wbase + inc - s;
#pragma unroll
    for (int j = 0; j < 8; ++j) {
        unsigned c = vals[j];
        if (run < t0 && run + c >= t0) { res[0] = t * 8 + j; res[1] = run; }
        if (t1 && run < t1 && run + c >= t1) { res[2] = t * 8 + j; res[3] = run; }
        run += c;
    }
    __syncthreads();
}

// ---- 1: fixed-threshold single-pass collect; per-block slots (no global atomics) ----
__global__ void __launch_bounds__(256) k_collect(
        const float4* __restrict__ loc, const float* __restrict__ score,
        const float4* __restrict__ anchor, const int* __restrict__ ph,
        const int* __restrict__ pw, int n,
        u64* __restrict__ candA, unsigned* __restrict__ candW,
        unsigned* __restrict__ vW, unsigned* __restrict__ cnts) {
    __shared__ u64 win[KCAP];
    __shared__ unsigned sNW, sVW;
    const int tid = threadIdx.x, bid = blockIdx.x;
    if (tid == 0) { sNW = 0; sVW = 0; }
    if (bid == 0 && tid == 0) cnts[6] = 0;    // done-counter for k_rankmat
    __syncthreads();
    const int gtid = bid * 256 + tid;
    const int T = GRIDC * 256;
    const float ih = (float)ph[0], iw = (float)pw[0];
    const int n4 = n >> 2, ntail = n4 << 2;
    const float4* s4 = (const float4*)score;
    for (int idx0 = gtid; idx0 < n4; idx0 += T * 8) {
        float4 v[8]; int ok[8];
#pragma unroll
        for (int k = 0; k < 8; ++k) {
            int idx = idx0 + k * T;
            ok[k] = idx < n4;
            v[k] = ok[k] ? s4[idx] : make_float4(0.f, 0.f, 0.f, 0.f);
        }
#pragma unroll
        for (int k = 0; k < 8; ++k) if (ok[k]) {
            float sc[4] = {v[k].x, v[k].y, v[k].z, v[k].w};
            int ib = (idx0 + k * T) << 2;
#pragma unroll
            for (int c = 0; c < 4; ++c) {
                if (sc[c] > TFIX) {
                    int i = ib + c;
                    float4 r = decode_box(anchor[i], loc[i], ih, iw);
                    bool valid = ((r.z - r.x) >= MINSZ) && ((r.w - r.y) >= MINSZ);
                    float ms = valid ? sc[c] : -__builtin_inff();
                    u64 key = ((u64)inv_key(ms) << 32) | (unsigned)i;
                    unsigned p = atomicAdd(&sNW, 1u);
                    if (p < KCAP) win[p] = key;
                    if (valid) atomicAdd(&sVW, 1u);
                }
            }
        }
    }
    for (int i = ntail + gtid; i < n; i += T) {
        float s = score[i];
        if (s > TFIX) {
            float4 r = decode_box(anchor[i], loc[i], ih, iw);
            bool valid = ((r.z - r.x) >= MINSZ) && ((r.w - r.y) >= MINSZ);
            float ms = valid ? s : -__builtin_inff();
            u64 key = ((u64)inv_key(ms) << 32) | (unsigned)i;
            unsigned p = atomicAdd(&sNW, 1u);
            if (p < KCAP) win[p] = key;
            if (valid) atomicAdd(&sVW, 1u);
        }
    }
    __syncthreads();
    unsigned NW = sNW;
    unsigned NWc = NW < KCAP ? NW : KCAP;
    for (int i = tid; i < KCAP; i += 256)
        candA[bid * KCAP + i] = (i < (int)NWc) ? win[i] : ~0ULL;
    if (tid == 0) { candW[bid] = NW; vW[bid] = sVW; }   // written EVERY call
}

struct SmC {
    u64 skey[MT];            // 32 KB
    unsigned shist[NBIN];    // 8 KB
    unsigned sprefix[NBIN];  // 8 KB
};
struct SmFb {
    u64   lk[CAP6];          // 64 KB
    float y1[NPOST], x1[NPOST], y2[NPOST], x2[NPOST], ar[NPOST];
};
union SmR { SmC c; SmFb fb; };

// ---- 2: 9 blocks: counting-sort rank -> decode -> transposed matrix -> last-block scan ----
__global__ void __launch_bounds__(256) k_rankmat(
        const float4* __restrict__ loc, const float* __restrict__ score,
        const float4* __restrict__ anchor, const int* __restrict__ ph,
        const int* __restrict__ pw, int n,
        const u64* __restrict__ candA, const unsigned* __restrict__ candW,
        const unsigned* __restrict__ vW, u64* __restrict__ cand6,
        unsigned* __restrict__ cnts, u64* __restrict__ gmatT,
        unsigned* __restrict__ order6, float4* __restrict__ roi6,
        float* __restrict__ out) {
    __shared__ SmR sm;
    __shared__ float4 sroi[CA];
    __shared__ float  sarea[CA];
    __shared__ unsigned svalid[CA / 32];
    __shared__ unsigned swave[8], res[8];
    __shared__ unsigned sInvLo, sCW, sVV, sOvf, sFNW;
    __shared__ int sIsLast;
    __shared__ u64 skm[NG];
    __shared__ int snk, sflag;
    int tid = threadIdx.x;
    float ih = (float)ph[0], iw = (float)pw[0];

    if (tid == 0) { sCW = 0; sVV = 0; sOvf = 0; sInvLo = 0xFFFFFFFFu; }
    __syncthreads();
    if (tid < GRIDC) {
        unsigned w = candW[tid];
        if (w > KCAP) atomicOr(&sOvf, 1u);
        atomicAdd(&sVV, vW[tid]);
    }
    __syncthreads();
    const bool mainValid = (sOvf == 0u) && (sVV >= (unsigned)CA);

    if (mainValid) {
        for (int b = tid; b < NBIN; b += 256) sm.c.shist[b] = 0;
        for (int r = tid; r < CA; r += 256) { sroi[r] = make_float4(0.f,0.f,0.f,0.f); sarea[r] = 0.f; }
        if (tid < CA / 32) svalid[tid] = 0;
        u64 kreg[16];
#pragma unroll
        for (int k = 0; k < 16; ++k) kreg[k] = candA[tid + k * 256];
        unsigned mymin = 0xFFFFFFFFu;
#pragma unroll
        for (int k = 0; k < 16; ++k) {
            unsigned hi = (unsigned)(kreg[k] >> 32);
            mymin = mymin < hi ? mymin : hi;
        }
#pragma unroll
        for (int off = 32; off; off >>= 1) {
            unsigned o = (unsigned)__shfl_down((int)mymin, off, 64);
            mymin = mymin < o ? mymin : o;
        }
        if ((tid & 63) == 0) atomicMin(&sInvLo, mymin);
        __syncthreads();
        unsigned invLo = sInvLo;
#pragma unroll
        for (int k = 0; k < 16; ++k) {
            unsigned dd = ((unsigned)(kreg[k] >> 32) - invLo) >> 3;
            atomicAdd(&sm.c.shist[dd > 2047u ? 2047u : dd], 1u);
        }
        __syncthreads();
        {   // fast exclusive prefix into sprefix
            unsigned vals[8], s = 0;
#pragma unroll
            for (int j = 0; j < 8; ++j) { vals[j] = sm.c.shist[tid * 8 + j]; s += vals[j]; }
            unsigned inc = s;
#pragma unroll
            for (int off = 1; off < 64; off <<= 1) {
                unsigned o = (unsigned)__shfl_up((int)inc, off, 64);
                if ((tid & 63) >= off) inc += o;
            }
            if ((tid & 63) == 63) swave[tid >> 6] = inc;
            __syncthreads();
            unsigned wbase = 0;
            for (int w = 0; w < (tid >> 6); ++w) wbase += swave[w];
            unsigned run = wbase + inc - s;
#pragma unroll
            for (int j = 0; j < 8; ++j) { sm.c.sprefix[tid * 8 + j] = run; run += vals[j]; }
        }
        __syncthreads();
#pragma unroll
        for (int k = 0; k < 16; ++k) {
            unsigned dd = ((unsigned)(kreg[k] >> 32) - invLo) >> 3;
            dd = dd > 2047u ? 2047u : dd;
            unsigned pos = atomicAdd(&sm.c.sprefix[dd], 1u);
            sm.c.skey[pos] = kreg[k];
        }
        __syncthreads();
#pragma unroll
        for (int k = 0; k < 16; ++k) {
            unsigned p = tid + k * 256u;
            u64 key = sm.c.skey[p];
            if (key == ~0ULL) continue;                  // sentinel
            unsigned dd = ((unsigned)(key >> 32) - invLo) >> 3;
            dd = dd > 2047u ? 2047u : dd;
            unsigned e = sm.c.sprefix[dd];
            unsigned s0 = e - sm.c.shist[dd];
            if (s0 >= (unsigned)CA) continue;            // rank >= s0 >= CA: skip
            int rank = (int)s0;
            for (unsigned q = s0; q < e; ++q) rank += (sm.c.skey[q] < key) ? 1 : 0;
            if (rank < CA) {
                unsigned idx = (unsigned)key;
                float4 b = decode_box(anchor[idx], loc[idx], ih, iw);
                sroi[rank] = b;
                sarea[rank] = (b.z - b.x) * (b.w - b.y);
                if (((b.z - b.x) >= MINSZ) && ((b.w - b.y) >= MINSZ))
                    atomicOr(&svalid[rank >> 5], 1u << (rank & 31));
            }
        }
        __syncthreads();
        // transposed matrix slice: gmatT[gr*CA + jcol] bit c = row 64*gr+c suppresses col jcol
        {
            int task = blockIdx.x * 256 + tid;
            int gr = task / CA;
            int jcol = task - gr * CA;
            int j0 = gr << 6;
            u64 bits = 0;
            if (j0 < jcol) {
                float4 b = sroi[jcol];
                float ab = sarea[jcol];
                int cmax = jcol - j0; cmax = cmax > 64 ? 64 : cmax;
                for (int c = 0; c < cmax; ++c) {
                    int row = j0 + c;
                    float4 r = sroi[row];
                    float yy1 = fmaxf(r.x, b.x);
                    float xx1 = fmaxf(r.y, b.y);
                    float yy2 = fminf(r.z, b.z);
                    float xx2 = fminf(r.w, b.w);
                    float inter = fmaxf(yy2 - yy1, 0.0f) * fmaxf(xx2 - xx1, 0.0f);
                    float iou = inter / (sarea[row] + ab - inter);  // ref op order
                    if (iou > NMS_T) bits |= (1ULL << c);
                }
            }
            gmatT[gr * CA + jcol] = bits;
        }
    }
    // arrive-only done counter; last block continues alone
    __threadfence();
    __syncthreads();
    if (tid == 0) {
        unsigned d = atomicAdd(&cnts[6], 1u);
        sIsLast = (d == GRIDR - 1);
    }
    __syncthreads();
    if (!sIsLast) return;
    __threadfence();   // acquire

    // ---- ballot scan ----
    int Ceff = CA;     // mainValid guarantees >= CA correctly-ranked candidates
    if (tid < 64 && mainValid) {
        u64 supfut[NG], W[NG], nxtW[NG], kmask[NG];
#pragma unroll
        for (int w = 0; w < NG; ++w) {
            supfut[w] = ~(((u64)svalid[2 * w + 1] << 32) | (u64)svalid[2 * w]);
            kmask[w] = 0ull;
        }
#pragma unroll
        for (int gq = 0; gq < NG; ++gq) W[gq] = gmatT[0 * CA + 64 * gq + tid];
        int nk = 0;
        bool done = false;
#pragma unroll
        for (int g = 0; g < NG; ++g) {
            if (g < NG - 1) {
#pragma unroll
                for (int gq = 0; gq < NG; ++gq) nxtW[gq] = gmatT[(g + 1) * CA + 64 * gq + tid];
            }
            int base = 64 * g;
            if (!done && base < Ceff) {
                u64 bound = (Ceff - base >= 64) ? ~0ull : ((1ull << (Ceff - base)) - 1ull);
                u64 live = ~supfut[g] & bound;
                u64 km = 0;
                while (live) {
                    int b = (int)__builtin_ctzll(live);
                    km |= 1ull << b;
                    ++nk;
                    if (nk == NPOST) { done = true; break; }
                    bool s = (W[g] >> b) & 1ull;
                    u64 supm = __ballot(s);
                    live &= ~(supm | (1ull << b));
                }
                kmask[g] = km;
                if (!done && g < NG - 1) {
#pragma unroll
                    for (int gq = 0; gq < NG; ++gq) {
                        if (gq > g) {
                            bool any = (W[gq] & km) != 0ull;
                            supfut[gq] |= __ballot(any);
                        }
                    }
                }
            }
#pragma unroll
            for (int gq = 0; gq < NG; ++gq) W[gq] = nxtW[gq];
        }
        if (tid == 0) {
            snk = nk;
            sflag = (nk < NPOST) ? 1 : 0;
#pragma unroll
            for (int g = 0; g < NG; ++g) skm[g] = kmask[g];
        }
    }
    if (tid == 0 && !mainValid) {
        snk = 0; sflag = 1;
#pragma unroll
        for (int g = 0; g < NG; ++g) skm[g] = 0ull;
    }
    __syncthreads();
    int nk = snk, flag = sflag;
    float4* out4 = (float4*)out;
    if (!flag) {
        int basepc[NG];
        {
            int run = 0;
#pragma unroll
            for (int g = 0; g < NG; ++g) { basepc[g] = run; run += __popcll(skm[g]); }
        }
        int wv = tid >> 6, j = tid & 63;
#pragma unroll
        for (int gg = 0; gg < 2; ++gg) {
            int g = wv + 4 * gg;
            if (g < NG) {
                u64 km = skm[g];
                if ((km >> j) & 1ull) {
                    int rank = basepc[g] + __popcll(km & ((1ull << j) - 1ull));
                    if (rank < NPOST) out4[rank] = sroi[64 * g + j];
                }
            }
        }
        for (int k = nk + tid; k < NPOST; k += 256) out4[k] = make_float4(0.f,0.f,0.f,0.f);
        return;
    }
    // ---------- exact fallback (gated; never taken on sane data) ----------
    // build own score histogram (single block; slow but exact), find b6 @ rank NPRE
    __syncthreads();
    for (int b = tid; b < NBIN; b += 256) sm.c.shist[b] = 0;
    __syncthreads();
    for (int i = tid; i < n; i += 256) atomicAdd(&sm.c.shist[sbin_of(score[i])], 1u);
    __syncthreads();
    fastscan2048(sm.c.shist, NPRE, 0, swave, res);
    unsigned b6 = res[0];
    if (tid == 0) sFNW = 0;
    __syncthreads();
    for (int i = tid; i < n; i += 256) {
        float s = score[i];
        if ((unsigned)sbin_of(s) <= b6) {
            float4 r = decode_box(anchor[i], loc[i], ih, iw);
            bool valid = ((r.z - r.x) >= MINSZ) && ((r.w - r.y) >= MINSZ);
            float ms = valid ? s : -__builtin_inff();
            u64 key = ((u64)inv_key(ms) << 32) | (unsigned)i;
            unsigned p = atomicAdd(&sFNW, 1u);
            if (p < CAP6) cand6[p] = key;
        }
    }
    __threadfence();
    __syncthreads();
    unsigned M = sFNW < (unsigned)CAP6 ? sFNW : (unsigned)CAP6;
    for (unsigned i = tid; i < CAP6; i += 256) sm.fb.lk[i] = (i < M) ? cand6[i] : ~0ULL;
    for (int r = tid; r < NPRE; r += 256) order6[r] = 0xFFFFFFFFu;
    __syncthreads();
    for (unsigned c = tid; c < M; c += 256) {
        u64 key = sm.fb.lk[c];
        int rank = 0;
        for (unsigned j = 0; j < M; ++j) rank += (sm.fb.lk[j] < key) ? 1 : 0;
        if (rank < NPRE) order6[rank] = (unsigned)key;
    }
    __syncthreads();
    for (int r = tid; r < NPRE; r += 256) {
        unsigned idx = order6[r];
        float4 b = make_float4(0.f, 0.f, 0.f, 0.f);
        if (idx < (unsigned)n) b = decode_box(anchor[idx], loc[idx], ih, iw);
        roi6[r] = b;
    }
    __syncthreads();
    if (tid < 64) {
        int lane = tid;
        int nk2 = 0;
        for (int i = 0; i < NPRE; i++) {
            float4 b = roi6[i];
            float hs = b.z - b.x, wd = b.w - b.y;
            if (!(hs >= MINSZ && wd >= MINSZ)) continue;
            float ab = hs * wd;
            bool sup = false;
            for (int base = 0; base < nk2 && !sup; base += 64) {
                int t = base + lane;
                bool s = false;
                if (t < nk2) {
                    float yy1 = fmaxf(b.x, sm.fb.y1[t]);
                    float xx1 = fmaxf(b.y, sm.fb.x1[t]);
                    float yy2 = fminf(b.z, sm.fb.y2[t]);
                    float xx2 = fminf(b.w, sm.fb.x2[t]);
                    float inter = fmaxf(yy2 - yy1, 0.0f) * fmaxf(xx2 - xx1, 0.0f);
                    float iou = inter / (sm.fb.ar[t] + ab - inter);
                    s = iou > NMS_T;
                }
                sup = (__ballot(s) != 0ULL);
            }
            if (!sup) {
                if (lane == 0) {
                    sm.fb.y1[nk2] = b.x; sm.fb.x1[nk2] = b.y;
                    sm.fb.y2[nk2] = b.z; sm.fb.x2[nk2] = b.w; sm.fb.ar[nk2] = ab;
                }
                nk2++;
                if (nk2 == NPOST) break;
            }
        }
        for (int k = lane; k < NPOST; k += 64) {
            float4 o = make_float4(0.f, 0.f, 0.f, 0.f);
            if (k < nk2) o = make_float4(sm.fb.y1[k], sm.fb.x1[k], sm.fb.y2[k], sm.fb.x2[k]);
            out4[k] = o;
        }
    }
}

extern "C" void kernel_launch(void* const* d_in, const int* in_sizes, int n_in,
                              void* d_out, int out_size, void* d_ws, size_t ws_size,
                              hipStream_t stream) {
    const float4* loc    = (const float4*)d_in[0];
    const float*  score  = (const float*)d_in[1];
    const float4* anchor = (const float4*)d_in[2];
    const int*    ph     = (const int*)d_in[3];
    const int*    pw     = (const int*)d_in[4];
    int n = in_sizes[1];

    char* ws = (char*)d_ws;
    u64*      cand6  = (u64*)(ws + OFF_CAND6);
    u64*      candA  = (u64*)(ws + OFF_CANDA);
    unsigned* candW  = (unsigned*)(ws + OFF_CANDW);
    unsigned* vW     = (unsigned*)(ws + OFF_VW);
    unsigned* order6 = (unsigned*)(ws + OFF_ORDER6);
    float4*   roi6   = (float4*)(ws + OFF_ROI6);
    u64*      gmatT  = (u64*)(ws + OFF_GMAT);
    unsigned* cnts   = (unsigned*)(ws + OFF_CNT);
    float* out = (float*)d_out;

    k_collect <<<dim3(GRIDC), dim3(256), 0, stream>>>(loc, score, anchor, ph, pw, n,
                                                      candA, candW, vW, cnts);
    k_rankmat <<<dim3(GRIDR), dim3(256), 0, stream>>>(loc, score, anchor, ph, pw, n,
                                                      candA, candW, vW, cand6, cnts,
                                                      gmatT, order6, roi6, out);
}

// Round 21
// 50.784 us; speedup vs baseline: 1.4742x; 1.0705x over previous
//
#include <hip/hip_runtime.h>
#include <stdint.h>

typedef unsigned long long u64;

#define NMS_T 0.7f
#define MINSZ 16.0f
#define NPRE 6000
#define NPOST 300
#define CA   384
#define NG   6          // groups of 64 = CA/64
#define CAP6 8192
#define NBIN 2048
#define GRIDC 128
#define GRIDR 9         // NG*CA/256
#define KCAP 32         // winner slots per collect block
#define MT   (GRIDC*KCAP)   // 4096 candidate slots (sentinel-padded)
#define TFIX 0.9990234375f  // 1 - 1024/2^20; E[winners]=1024 on U[0,1)
#define SENT (~0ULL)        // sentinel; genuine keys can never equal this

// ---- workspace layout (bytes) ----
#define OFF_CAND6  0                          // CAP6*8 (fallback only)
#define OFF_CANDA  (OFF_CAND6 + CAP6*8)       // MT*8 = 32768
#define OFF_CANDW  (OFF_CANDA + MT*8)         // GRIDC*4 (written every call)
#define OFF_VW     (OFF_CANDW + GRIDC*4)      // GRIDC*4 (written every call)
#define OFF_ORDER6 (OFF_VW + GRIDC*4)         // NPRE*4  (fallback)
#define OFF_ROI6   (OFF_ORDER6 + NPRE*4)      // NPRE*16 (fallback)
#define OFF_GMAT   (OFF_ROI6 + NPRE*16)       // NG*CA*8 transposed gmatT[gr*CA+col]
#define OFF_CNT    (OFF_GMAT + NG*CA*8)       // 32: [6]=done2 (zeroed by k_collect blk0)

__device__ __forceinline__ unsigned inv_key(float s) {
    unsigned u = __float_as_uint(s);
    unsigned k = (u & 0x80000000u) ? ~u : (u | 0x80000000u);
    return ~k;   // ascending inv == descending score
}

__device__ __forceinline__ float4 decode_box(const float4 a, const float4 l,
                                             float ih, float iw) {
    float h  = a.z - a.x;
    float w  = a.w - a.y;
    float cy = a.x + 0.5f * h;
    float cx = a.y + 0.5f * w;
    float ncy = l.x * h + cy;
    float ncx = l.y * w + cx;
    float nh  = expf(l.z) * h;
    float nw  = expf(l.w) * w;
    float y1 = fminf(fmaxf(ncy - 0.5f * nh, 0.0f), ih);
    float x1 = fminf(fmaxf(ncx - 0.5f * nw, 0.0f), iw);
    float y2 = fminf(fmaxf(ncy + 0.5f * nh, 0.0f), ih);
    float x2 = fminf(fmaxf(ncx + 0.5f * nw, 0.0f), iw);
    return make_float4(y1, x1, y2, x2);
}

__device__ __forceinline__ int sbin_of(float s) {
    int b = (int)(s * 2048.0f);
    b = b < 0 ? 0 : (b > 2047 ? 2047 : b);
    return 2047 - b;           // ascending = descending score
}

// fast block scan of 2048-bin histogram (2 barriers): bins containing ranks t0/t1
__device__ void fastscan2048(const unsigned* __restrict__ h, unsigned t0, unsigned t1,
                             unsigned* swave, unsigned* res) {
    int t = threadIdx.x;
    unsigned vals[8], s = 0;
#pragma unroll
    for (int j = 0; j < 8; ++j) { vals[j] = h[t * 8 + j]; s += vals[j]; }
    unsigned inc = s;
#pragma unroll
    for (int off = 1; off < 64; off <<= 1) {
        unsigned o = (unsigned)__shfl_up((int)inc, off, 64);
        if ((t & 63) >= off) inc += o;
    }
    if ((t & 63) == 63) swave[t >> 6] = inc;
    __syncthreads();
    unsigned wbase = 0;
    for (int w = 0; w < (t >> 6); ++w) wbase += swave[w];
    unsigned run = wbase + inc - s;
#pragma unroll
    for (int j = 0; j < 8; ++j) {
        unsigned c = vals[j];
        if (run < t0 && run + c >= t0) { res[0] = t * 8 + j; res[1] = run; }
        if (t1 && run < t1 && run + c >= t1) { res[2] = t * 8 + j; res[3] = run; }
        run += c;
    }
    __syncthreads();
}

// ---- 1: fixed-threshold single-pass collect; per-block slots (no global atomics) ----
__global__ void __launch_bounds__(256) k_collect(
        const float4* __restrict__ loc, const float* __restrict__ score,
        const float4* __restrict__ anchor, const int* __restrict__ ph,
        const int* __restrict__ pw, int n,
        u64* __restrict__ candA, unsigned* __restrict__ candW,
        unsigned* __restrict__ vW, unsigned* __restrict__ cnts) {
    __shared__ u64 win[KCAP];
    __shared__ unsigned sNW, sVW;
    const int tid = threadIdx.x, bid = blockIdx.x;
    if (tid == 0) { sNW = 0; sVW = 0; }
    if (bid == 0 && tid == 0) cnts[6] = 0;    // done-counter for k_rankmat
    __syncthreads();
    const int gtid = bid * 256 + tid;
    const int T = GRIDC * 256;
    const float ih = (float)ph[0], iw = (float)pw[0];
    const int n4 = n >> 2, ntail = n4 << 2;
    const float4* s4 = (const float4*)score;
    for (int idx0 = gtid; idx0 < n4; idx0 += T * 8) {
        float4 v[8]; int ok[8];
#pragma unroll
        for (int k = 0; k < 8; ++k) {
            int idx = idx0 + k * T;
            ok[k] = idx < n4;
            v[k] = ok[k] ? s4[idx] : make_float4(0.f, 0.f, 0.f, 0.f);
        }
#pragma unroll
        for (int k = 0; k < 8; ++k) if (ok[k]) {
            float sc[4] = {v[k].x, v[k].y, v[k].z, v[k].w};
            int ib = (idx0 + k * T) << 2;
#pragma unroll
            for (int c = 0; c < 4; ++c) {
                if (sc[c] > TFIX) {
                    int i = ib + c;
                    float4 r = decode_box(anchor[i], loc[i], ih, iw);
                    bool valid = ((r.z - r.x) >= MINSZ) && ((r.w - r.y) >= MINSZ);
                    float ms = valid ? sc[c] : -__builtin_inff();
                    u64 key = ((u64)inv_key(ms) << 32) | (unsigned)i;
                    unsigned p = atomicAdd(&sNW, 1u);
                    if (p < KCAP) win[p] = key;
                    if (valid) atomicAdd(&sVW, 1u);
                }
            }
        }
    }
    for (int i = ntail + gtid; i < n; i += T) {
        float s = score[i];
        if (s > TFIX) {
            float4 r = decode_box(anchor[i], loc[i], ih, iw);
            bool valid = ((r.z - r.x) >= MINSZ) && ((r.w - r.y) >= MINSZ);
            float ms = valid ? s : -__builtin_inff();
            u64 key = ((u64)inv_key(ms) << 32) | (unsigned)i;
            unsigned p = atomicAdd(&sNW, 1u);
            if (p < KCAP) win[p] = key;
            if (valid) atomicAdd(&sVW, 1u);
        }
    }
    __syncthreads();
    unsigned NW = sNW;
    unsigned NWc = NW < KCAP ? NW : KCAP;
    for (int i = tid; i < KCAP; i += 256)
        candA[bid * KCAP + i] = (i < (int)NWc) ? win[i] : SENT;
    if (tid == 0) { candW[bid] = NW; vW[bid] = sVW; }   // written EVERY call
}

struct SmC {
    u64 skey[MT];            // 32 KB
    unsigned shist[NBIN];    // 8 KB
    unsigned sprefix[NBIN];  // 8 KB
};
struct SmFb {
    u64   lk[CAP6];          // 64 KB
    float y1[NPOST], x1[NPOST], y2[NPOST], x2[NPOST], ar[NPOST];
};
union SmR { SmC c; SmFb fb; };

// ---- 2: 9 blocks: counting-sort rank (sentinel-skipping) -> decode -> matrix -> scan ----
__global__ void __launch_bounds__(256) k_rankmat(
        const float4* __restrict__ loc, const float* __restrict__ score,
        const float4* __restrict__ anchor, const int* __restrict__ ph,
        const int* __restrict__ pw, int n,
        const u64* __restrict__ candA, const unsigned* __restrict__ candW,
        const unsigned* __restrict__ vW, u64* __restrict__ cand6,
        unsigned* __restrict__ cnts, u64* __restrict__ gmatT,
        unsigned* __restrict__ order6, float4* __restrict__ roi6,
        float* __restrict__ out) {
    __shared__ SmR sm;
    __shared__ float4 sroi[CA];
    __shared__ float  sarea[CA];
    __shared__ unsigned svalid[CA / 32];
    __shared__ unsigned swave[8], res[8];
    __shared__ unsigned sInvLo, sVV, sOvf, sFNW;
    __shared__ int sIsLast;
    __shared__ u64 skm[NG];
    __shared__ int snk, sflag;
    int tid = threadIdx.x;
    float ih = (float)ph[0], iw = (float)pw[0];

    if (tid == 0) { sVV = 0; sOvf = 0; sInvLo = 0xFFFFFFFFu; }
    __syncthreads();
    if (tid < GRIDC) {
        unsigned w = candW[tid];
        if (w > KCAP) atomicOr(&sOvf, 1u);
        atomicAdd(&sVV, vW[tid]);
    }
    __syncthreads();
    const bool mainValid = (sOvf == 0u) && (sVV >= (unsigned)CA);

    if (mainValid) {
        for (int b = tid; b < NBIN; b += 256) sm.c.shist[b] = 0;
        for (int r = tid; r < CA; r += 256) { sroi[r] = make_float4(0.f,0.f,0.f,0.f); sarea[r] = 0.f; }
        if (tid < CA / 32) svalid[tid] = 0;
        u64 kreg[16];
#pragma unroll
        for (int k = 0; k < 16; ++k) {
            kreg[k] = candA[tid + k * 256];
            sm.c.skey[tid + k * 256] = SENT;     // pre-init; unscattered slots stay sentinel
        }
        unsigned mymin = 0xFFFFFFFFu;
#pragma unroll
        for (int k = 0; k < 16; ++k) {
            if (kreg[k] != SENT) {
                unsigned hi = (unsigned)(kreg[k] >> 32);
                mymin = mymin < hi ? mymin : hi;
            }
        }
#pragma unroll
        for (int off = 32; off; off >>= 1) {
            unsigned o = (unsigned)__shfl_down((int)mymin, off, 64);
            mymin = mymin < o ? mymin : o;
        }
        if ((tid & 63) == 0) atomicMin(&sInvLo, mymin);
        __syncthreads();
        unsigned invLo = sInvLo;
        // histogram REAL keys only (sentinels skipped -> no same-bin contention)
#pragma unroll
        for (int k = 0; k < 16; ++k) {
            if (kreg[k] != SENT) {
                unsigned dd = ((unsigned)(kreg[k] >> 32) - invLo) >> 3;
                atomicAdd(&sm.c.shist[dd > 2047u ? 2047u : dd], 1u);
            }
        }
        __syncthreads();
        {   // fast exclusive prefix into sprefix
            unsigned vals[8], s = 0;
#pragma unroll
            for (int j = 0; j < 8; ++j) { vals[j] = sm.c.shist[tid * 8 + j]; s += vals[j]; }
            unsigned inc = s;
#pragma unroll
            for (int off = 1; off < 64; off <<= 1) {
                unsigned o = (unsigned)__shfl_up((int)inc, off, 64);
                if ((tid & 63) >= off) inc += o;
            }
            if ((tid & 63) == 63) swave[tid >> 6] = inc;
            __syncthreads();
            unsigned wbase = 0;
            for (int w = 0; w < (tid >> 6); ++w) wbase += swave[w];
            unsigned run = wbase + inc - s;
#pragma unroll
            for (int j = 0; j < 8; ++j) { sm.c.sprefix[tid * 8 + j] = run; run += vals[j]; }
        }
        __syncthreads();
        // scatter REAL keys only
#pragma unroll
        for (int k = 0; k < 16; ++k) {
            if (kreg[k] != SENT) {
                unsigned dd = ((unsigned)(kreg[k] >> 32) - invLo) >> 3;
                dd = dd > 2047u ? 2047u : dd;
                unsigned pos = atomicAdd(&sm.c.sprefix[dd], 1u);
                sm.c.skey[pos] = kreg[k];
            }
        }
        __syncthreads();
#pragma unroll
        for (int k = 0; k < 16; ++k) {
            unsigned p = tid + k * 256u;
            u64 key = sm.c.skey[p];
            if (key == SENT) continue;
            unsigned dd = ((unsigned)(key >> 32) - invLo) >> 3;
            dd = dd > 2047u ? 2047u : dd;
            unsigned e = sm.c.sprefix[dd];
            unsigned s0 = e - sm.c.shist[dd];
            if (s0 >= (unsigned)CA) continue;            // rank >= s0 >= CA: skip
            int rank = (int)s0;
            for (unsigned q = s0; q < e; ++q) rank += (sm.c.skey[q] < key) ? 1 : 0;
            if (rank < CA) {
                unsigned idx = (unsigned)key;
                float4 b = decode_box(anchor[idx], loc[idx], ih, iw);
                sroi[rank] = b;
                sarea[rank] = (b.z - b.x) * (b.w - b.y);
                if (((b.z - b.x) >= MINSZ) && ((b.w - b.y) >= MINSZ))
                    atomicOr(&svalid[rank >> 5], 1u << (rank & 31));
            }
        }
        __syncthreads();
        // transposed matrix slice: gmatT[gr*CA + jcol] bit c = row 64*gr+c suppresses col jcol
        {
            int task = blockIdx.x * 256 + tid;
            int gr = task / CA;
            int jcol = task - gr * CA;
            int j0 = gr << 6;
            u64 bits = 0;
            if (j0 < jcol) {
                float4 b = sroi[jcol];
                float ab = sarea[jcol];
                int cmax = jcol - j0; cmax = cmax > 64 ? 64 : cmax;
                for (int c = 0; c < cmax; ++c) {
                    int row = j0 + c;
                    float4 r = sroi[row];
                    float yy1 = fmaxf(r.x, b.x);
                    float xx1 = fmaxf(r.y, b.y);
                    float yy2 = fminf(r.z, b.z);
                    float xx2 = fminf(r.w, b.w);
                    float inter = fmaxf(yy2 - yy1, 0.0f) * fmaxf(xx2 - xx1, 0.0f);
                    float iou = inter / (sarea[row] + ab - inter);  // ref op order
                    if (iou > NMS_T) bits |= (1ULL << c);
                }
            }
            gmatT[gr * CA + jcol] = bits;
        }
    }
    // arrive-only done counter; last block continues alone
    __threadfence();
    __syncthreads();
    if (tid == 0) {
        unsigned d = atomicAdd(&cnts[6], 1u);
        sIsLast = (d == GRIDR - 1);
    }
    __syncthreads();
    if (!sIsLast) return;
    __threadfence();   // acquire

    // ---- ballot scan ----
    int Ceff = CA;     // mainValid guarantees >= CA correctly-ranked candidates
    if (tid < 64 && mainValid) {
        u64 supfut[NG], W[NG], nxtW[NG], kmask[NG];
#pragma unroll
        for (int w = 0; w < NG; ++w) {
            supfut[w] = ~(((u64)svalid[2 * w + 1] << 32) | (u64)svalid[2 * w]);
            kmask[w] = 0ull;
        }
#pragma unroll
        for (int gq = 0; gq < NG; ++gq) W[gq] = gmatT[0 * CA + 64 * gq + tid];
        int nk = 0;
        bool done = false;
#pragma unroll
        for (int g = 0; g < NG; ++g) {
            if (g < NG - 1) {
#pragma unroll
                for (int gq = 0; gq < NG; ++gq) nxtW[gq] = gmatT[(g + 1) * CA + 64 * gq + tid];
            }
            int base = 64 * g;
            if (!done && base < Ceff) {
                u64 bound = (Ceff - base >= 64) ? ~0ull : ((1ull << (Ceff - base)) - 1ull);
                u64 live = ~supfut[g] & bound;
                u64 km = 0;
                while (live) {
                    int b = (int)__builtin_ctzll(live);
                    km |= 1ull << b;
                    ++nk;
                    if (nk == NPOST) { done = true; break; }
                    bool s = (W[g] >> b) & 1ull;
                    u64 supm = __ballot(s);
                    live &= ~(supm | (1ull << b));
                }
                kmask[g] = km;
                if (!done && g < NG - 1) {
#pragma unroll
                    for (int gq = 0; gq < NG; ++gq) {
                        if (gq > g) {
                            bool any = (W[gq] & km) != 0ull;
                            supfut[gq] |= __ballot(any);
                        }
                    }
                }
            }
#pragma unroll
            for (int gq = 0; gq < NG; ++gq) W[gq] = nxtW[gq];
        }
        if (tid == 0) {
            snk = nk;
            sflag = (nk < NPOST) ? 1 : 0;
#pragma unroll
            for (int g = 0; g < NG; ++g) skm[g] = kmask[g];
        }
    }
    if (tid == 0 && !mainValid) {
        snk = 0; sflag = 1;
#pragma unroll
        for (int g = 0; g < NG; ++g) skm[g] = 0ull;
    }
    __syncthreads();
    int nk = snk, flag = sflag;
    float4* out4 = (float4*)out;
    if (!flag) {
        int basepc[NG];
        {
            int run = 0;
#pragma unroll
            for (int g = 0; g < NG; ++g) { basepc[g] = run; run += __popcll(skm[g]); }
        }
        int wv = tid >> 6, j = tid & 63;
#pragma unroll
        for (int gg = 0; gg < 2; ++gg) {
            int g = wv + 4 * gg;
            if (g < NG) {
                u64 km = skm[g];
                if ((km >> j) & 1ull) {
                    int rank = basepc[g] + __popcll(km & ((1ull << j) - 1ull));
                    if (rank < NPOST) out4[rank] = sroi[64 * g + j];
                }
            }
        }
        for (int k = nk + tid; k < NPOST; k += 256) out4[k] = make_float4(0.f,0.f,0.f,0.f);
        return;
    }
    // ---------- exact fallback (gated; never taken on sane data) ----------
    __syncthreads();
    for (int b = tid; b < NBIN; b += 256) sm.c.shist[b] = 0;
    __syncthreads();
    for (int i = tid; i < n; i += 256) atomicAdd(&sm.c.shist[sbin_of(score[i])], 1u);
    __syncthreads();
    fastscan2048(sm.c.shist, NPRE, 0, swave, res);
    unsigned b6 = res[0];
    if (tid == 0) sFNW = 0;
    __syncthreads();
    for (int i = tid; i < n; i += 256) {
        float s = score[i];
        if ((unsigned)sbin_of(s) <= b6) {
            float4 r = decode_box(anchor[i], loc[i], ih, iw);
            bool valid = ((r.z - r.x) >= MINSZ) && ((r.w - r.y) >= MINSZ);
            float ms = valid ? s : -__builtin_inff();
            u64 key = ((u64)inv_key(ms) << 32) | (unsigned)i;
            unsigned p = atomicAdd(&sFNW, 1u);
            if (p < CAP6) cand6[p] = key;
        }
    }
    __threadfence();
    __syncthreads();
    unsigned M = sFNW < (unsigned)CAP6 ? sFNW : (unsigned)CAP6;
    for (unsigned i = tid; i < CAP6; i += 256) sm.fb.lk[i] = (i < M) ? cand6[i] : ~0ULL;
    for (int r = tid; r < NPRE; r += 256) order6[r] = 0xFFFFFFFFu;
    __syncthreads();
    for (unsigned c = tid; c < M; c += 256) {
        u64 key = sm.fb.lk[c];
        int rank = 0;
        for (unsigned j = 0; j < M; ++j) rank += (sm.fb.lk[j] < key) ? 1 : 0;
        if (rank < NPRE) order6[rank] = (unsigned)key;
    }
    __syncthreads();
    for (int r = tid; r < NPRE; r += 256) {
        unsigned idx = order6[r];
        float4 b = make_float4(0.f, 0.f, 0.f, 0.f);
        if (idx < (unsigned)n) b = decode_box(anchor[idx], loc[idx], ih, iw);
        roi6[r] = b;
    }
    __syncthreads();
    if (tid < 64) {
        int lane = tid;
        int nk2 = 0;
        for (int i = 0; i < NPRE; i++) {
            float4 b = roi6[i];
            float hs = b.z - b.x, wd = b.w - b.y;
            if (!(hs >= MINSZ && wd >= MINSZ)) continue;
            float ab = hs * wd;
            bool sup = false;
            for (int base = 0; base < nk2 && !sup; base += 64) {
                int t = base + lane;
                bool s = false;
                if (t < nk2) {
                    float yy1 = fmaxf(b.x, sm.fb.y1[t]);
                    float xx1 = fmaxf(b.y, sm.fb.x1[t]);
                    float yy2 = fminf(b.z, sm.fb.y2[t]);
                    float xx2 = fminf(b.w, sm.fb.x2[t]);
                    float inter = fmaxf(yy2 - yy1, 0.0f) * fmaxf(xx2 - xx1, 0.0f);
                    float iou = inter / (sm.fb.ar[t] + ab - inter);
                    s = iou > NMS_T;
                }
                sup = (__ballot(s) != 0ULL);
            }
            if (!sup) {
                if (lane == 0) {
                    sm.fb.y1[nk2] = b.x; sm.fb.x1[nk2] = b.y;
                    sm.fb.y2[nk2] = b.z; sm.fb.x2[nk2] = b.w; sm.fb.ar[nk2] = ab;
                }
                nk2++;
                if (nk2 == NPOST) break;
            }
        }
        for (int k = lane; k < NPOST; k += 64) {
            float4 o = make_float4(0.f, 0.f, 0.f, 0.f);
            if (k < nk2) o = make_float4(sm.fb.y1[k], sm.fb.x1[k], sm.fb.y2[k], sm.fb.x2[k]);
            out4[k] = o;
        }
    }
}

extern "C" void kernel_launch(void* const* d_in, const int* in_sizes, int n_in,
                              void* d_out, int out_size, void* d_ws, size_t ws_size,
                              hipStream_t stream) {
    const float4* loc    = (const float4*)d_in[0];
    const float*  score  = (const float*)d_in[1];
    const float4* anchor = (const float4*)d_in[2];
    const int*    ph     = (const int*)d_in[3];
    const int*    pw     = (const int*)d_in[4];
    int n = in_sizes[1];

    char* ws = (char*)d_ws;
    u64*      cand6  = (u64*)(ws + OFF_CAND6);
    u64*      candA  = (u64*)(ws + OFF_CANDA);
    unsigned* candW  = (unsigned*)(ws + OFF_CANDW);
    unsigned* vW     = (unsigned*)(ws + OFF_VW);
    unsigned* order6 = (unsigned*)(ws + OFF_ORDER6);
    float4*   roi6   = (float4*)(ws + OFF_ROI6);
    u64*      gmatT  = (u64*)(ws + OFF_GMAT);
    unsigned* cnts   = (unsigned*)(ws + OFF_CNT);
    float* out = (float*)d_out;

    k_collect <<<dim3(GRIDC), dim3(256), 0, stream>>>(loc, score, anchor, ph, pw, n,
                                                      candA, candW, vW, cnts);
    k_rankmat <<<dim3(GRIDR), dim3(256), 0, stream>>>(loc, score, anchor, ph, pw, n,
                                                      candA, candW, vW, cand6, cnts,
                                                      gmatT, order6, roi6, out);
}

// Round 22
// 46.570 us; speedup vs baseline: 1.6076x; 1.0905x over previous
//
#include <hip/hip_runtime.h>
#include <stdint.h>

typedef unsigned long long u64;

#define NMS_T 0.7f
#define MINSZ 16.0f
#define NPRE 6000
#define NPOST 300
#define CA   384
#define NG   6          // groups of 64 = CA/64
#define CAP6 8192
#define NBIN 2048
#define GRIDC 128
#define GRIDR 9         // NG*CA/256
#define KCAP 32         // winner slots per collect block
#define MT   (GRIDC*KCAP)   // 4096 candidate slots (sentinel-padded)
#define TFIX 0.9990234375f  // 1 - 1024/2^20; E[winners]=1024 on U[0,1)
#define SENT (~0ULL)        // sentinel; genuine keys can never equal this

// ---- workspace layout (bytes) ----
#define OFF_CAND6  0                          // CAP6*8 (fallback only)
#define OFF_CANDA  (OFF_CAND6 + CAP6*8)       // MT*8 = 32768
#define OFF_CANDW  (OFF_CANDA + MT*8)         // GRIDC*4 (written every call)
#define OFF_VW     (OFF_CANDW + GRIDC*4)      // GRIDC*4 (written every call)
#define OFF_ORDER6 (OFF_VW + GRIDC*4)         // NPRE*4  (fallback)
#define OFF_ROI6   (OFF_ORDER6 + NPRE*4)      // NPRE*16 (fallback)
#define OFF_GMAT   (OFF_ROI6 + NPRE*16)       // NG*CA*8 transposed gmatT[gr*CA+col]
#define OFF_CNT    (OFF_GMAT + NG*CA*8)       // 32: [6]=done2 (zeroed by k_collect blk0)

__device__ __forceinline__ unsigned inv_key(float s) {
    unsigned u = __float_as_uint(s);
    unsigned k = (u & 0x80000000u) ? ~u : (u | 0x80000000u);
    return ~k;   // ascending inv == descending score
}

__device__ __forceinline__ float4 decode_box(const float4 a, const float4 l,
                                             float ih, float iw) {
    float h  = a.z - a.x;
    float w  = a.w - a.y;
    float cy = a.x + 0.5f * h;
    float cx = a.y + 0.5f * w;
    float ncy = l.x * h + cy;
    float ncx = l.y * w + cx;
    float nh  = expf(l.z) * h;
    float nw  = expf(l.w) * w;
    float y1 = fminf(fmaxf(ncy - 0.5f * nh, 0.0f), ih);
    float x1 = fminf(fmaxf(ncx - 0.5f * nw, 0.0f), iw);
    float y2 = fminf(fmaxf(ncy + 0.5f * nh, 0.0f), ih);
    float x2 = fminf(fmaxf(ncx + 0.5f * nw, 0.0f), iw);
    return make_float4(y1, x1, y2, x2);
}

__device__ __forceinline__ int sbin_of(float s) {
    int b = (int)(s * 2048.0f);
    b = b < 0 ? 0 : (b > 2047 ? 2047 : b);
    return 2047 - b;           // ascending = descending score
}

// fast block scan of 2048-bin histogram (2 barriers): bins containing ranks t0/t1
__device__ void fastscan2048(const unsigned* __restrict__ h, unsigned t0, unsigned t1,
                             unsigned* swave, unsigned* res) {
    int t = threadIdx.x;
    unsigned vals[8], s = 0;
#pragma unroll
    for (int j = 0; j < 8; ++j) { vals[j] = h[t * 8 + j]; s += vals[j]; }
    unsigned inc = s;
#pragma unroll
    for (int off = 1; off < 64; off <<= 1) {
        unsigned o = (unsigned)__shfl_up((int)inc, off, 64);
        if ((t & 63) >= off) inc += o;
    }
    if ((t & 63) == 63) swave[t >> 6] = inc;
    __syncthreads();
    unsigned wbase = 0;
    for (int w = 0; w < (t >> 6); ++w) wbase += swave[w];
    unsigned run = wbase + inc - s;
#pragma unroll
    for (int j = 0; j < 8; ++j) {
        unsigned c = vals[j];
        if (run < t0 && run + c >= t0) { res[0] = t * 8 + j; res[1] = run; }
        if (t1 && run < t1 && run + c >= t1) { res[2] = t * 8 + j; res[3] = run; }
        run += c;
    }
    __syncthreads();
}

// ---- 1: fixed-threshold single-pass collect; per-block slots (no global atomics) ----
__global__ void __launch_bounds__(256) k_collect(
        const float4* __restrict__ loc, const float* __restrict__ score,
        const float4* __restrict__ anchor, const int* __restrict__ ph,
        const int* __restrict__ pw, int n,
        u64* __restrict__ candA, unsigned* __restrict__ candW,
        unsigned* __restrict__ vW, unsigned* __restrict__ cnts) {
    __shared__ u64 win[KCAP];
    __shared__ unsigned sNW, sVW;
    const int tid = threadIdx.x, bid = blockIdx.x;
    if (tid == 0) { sNW = 0; sVW = 0; }
    if (bid == 0 && tid == 0) cnts[6] = 0;    // done-counter for k_rankmat
    __syncthreads();
    const int gtid = bid * 256 + tid;
    const int T = GRIDC * 256;
    const float ih = (float)ph[0], iw = (float)pw[0];
    const int n4 = n >> 2, ntail = n4 << 2;
    const float4* s4 = (const float4*)score;
    for (int idx0 = gtid; idx0 < n4; idx0 += T * 8) {
        float4 v[8]; int ok[8];
#pragma unroll
        for (int k = 0; k < 8; ++k) {
            int idx = idx0 + k * T;
            ok[k] = idx < n4;
            v[k] = ok[k] ? s4[idx] : make_float4(0.f, 0.f, 0.f, 0.f);
        }
#pragma unroll
        for (int k = 0; k < 8; ++k) if (ok[k]) {
            float sc[4] = {v[k].x, v[k].y, v[k].z, v[k].w};
            int ib = (idx0 + k * T) << 2;
#pragma unroll
            for (int c = 0; c < 4; ++c) {
                if (sc[c] > TFIX) {
                    int i = ib + c;
                    float4 r = decode_box(anchor[i], loc[i], ih, iw);
                    bool valid = ((r.z - r.x) >= MINSZ) && ((r.w - r.y) >= MINSZ);
                    float ms = valid ? sc[c] : -__builtin_inff();
                    u64 key = ((u64)inv_key(ms) << 32) | (unsigned)i;
                    unsigned p = atomicAdd(&sNW, 1u);
                    if (p < KCAP) win[p] = key;
                    if (valid) atomicAdd(&sVW, 1u);
                }
            }
        }
    }
    for (int i = ntail + gtid; i < n; i += T) {
        float s = score[i];
        if (s > TFIX) {
            float4 r = decode_box(anchor[i], loc[i], ih, iw);
            bool valid = ((r.z - r.x) >= MINSZ) && ((r.w - r.y) >= MINSZ);
            float ms = valid ? s : -__builtin_inff();
            u64 key = ((u64)inv_key(ms) << 32) | (unsigned)i;
            unsigned p = atomicAdd(&sNW, 1u);
            if (p < KCAP) win[p] = key;
            if (valid) atomicAdd(&sVW, 1u);
        }
    }
    __syncthreads();
    unsigned NW = sNW;
    unsigned NWc = NW < KCAP ? NW : KCAP;
    for (int i = tid; i < KCAP; i += 256)
        candA[bid * KCAP + i] = (i < (int)NWc) ? win[i] : SENT;
    if (tid == 0) { candW[bid] = NW; vW[bid] = sVW; }   // written EVERY call
}

struct SmC {
    u64 skey[MT];            // 32 KB
    unsigned shist[NBIN];    // 8 KB
    unsigned sprefix[NBIN];  // 8 KB
};
struct SmFb {
    u64   lk[CAP6];          // 64 KB
    float y1[NPOST], x1[NPOST], y2[NPOST], x2[NPOST], ar[NPOST];
};
union SmR { SmC c; SmFb fb; };

// ---- 2: 9 blocks: counting-sort rank (sentinel-skipping) -> decode -> matrix -> scan ----
__global__ void __launch_bounds__(256) k_rankmat(
        const float4* __restrict__ loc, const float* __restrict__ score,
        const float4* __restrict__ anchor, const int* __restrict__ ph,
        const int* __restrict__ pw, int n,
        const u64* __restrict__ candA, const unsigned* __restrict__ candW,
        const unsigned* __restrict__ vW, u64* __restrict__ cand6,
        unsigned* __restrict__ cnts, u64* __restrict__ gmatT,
        unsigned* __restrict__ order6, float4* __restrict__ roi6,
        float* __restrict__ out) {
    __shared__ SmR sm;
    __shared__ float4 sroi[CA];
    __shared__ float  sarea[CA];
    __shared__ unsigned svalid[CA / 32];
    __shared__ unsigned swave[8], res[8];
    __shared__ unsigned sInvLo, sVV, sOvf, sFNW;
    __shared__ int sIsLast;
    __shared__ u64 skm[NG];
    __shared__ int snk, sflag;
    int tid = threadIdx.x;
    float ih = (float)ph[0], iw = (float)pw[0];

    if (tid == 0) { sVV = 0; sOvf = 0; sInvLo = 0xFFFFFFFFu; }
    __syncthreads();
    // wave-reduced guard accumulation (2 LDS atomics total, not 128)
    {
        unsigned vv = 0, ovf = 0;
        if (tid < GRIDC) {
            unsigned w = candW[tid];
            ovf = (w > KCAP) ? 1u : 0u;
            vv = vW[tid];
        }
#pragma unroll
        for (int off = 32; off; off >>= 1) {
            vv  += (unsigned)__shfl_down((int)vv, off, 64);
            ovf |= (unsigned)__shfl_down((int)ovf, off, 64);
        }
        if (tid < GRIDC && (tid & 63) == 0) {
            atomicAdd(&sVV, vv);
            if (ovf) atomicOr(&sOvf, 1u);
        }
    }
    __syncthreads();
    const bool mainValid = (sOvf == 0u) && (sVV >= (unsigned)CA);

    if (mainValid) {
        for (int b = tid; b < NBIN; b += 256) sm.c.shist[b] = 0;
        for (int r = tid; r < CA; r += 256) { sroi[r] = make_float4(0.f,0.f,0.f,0.f); sarea[r] = 0.f; }
        if (tid < CA / 32) svalid[tid] = 0;
        u64 kreg[16];
#pragma unroll
        for (int k = 0; k < 16; ++k) {
            kreg[k] = candA[tid + k * 256];
            sm.c.skey[tid + k * 256] = SENT;     // pre-init; unscattered slots stay sentinel
        }
        unsigned mymin = 0xFFFFFFFFu;
#pragma unroll
        for (int k = 0; k < 16; ++k) {
            if (kreg[k] != SENT) {
                unsigned hi = (unsigned)(kreg[k] >> 32);
                mymin = mymin < hi ? mymin : hi;
            }
        }
#pragma unroll
        for (int off = 32; off; off >>= 1) {
            unsigned o = (unsigned)__shfl_down((int)mymin, off, 64);
            mymin = mymin < o ? mymin : o;
        }
        if ((tid & 63) == 0) atomicMin(&sInvLo, mymin);
        __syncthreads();
        unsigned invLo = sInvLo;
        // histogram REAL keys only (sentinels skipped -> no same-bin contention)
#pragma unroll
        for (int k = 0; k < 16; ++k) {
            if (kreg[k] != SENT) {
                unsigned dd = ((unsigned)(kreg[k] >> 32) - invLo) >> 3;
                atomicAdd(&sm.c.shist[dd > 2047u ? 2047u : dd], 1u);
            }
        }
        __syncthreads();
        {   // fast exclusive prefix into sprefix
            unsigned vals[8], s = 0;
#pragma unroll
            for (int j = 0; j < 8; ++j) { vals[j] = sm.c.shist[tid * 8 + j]; s += vals[j]; }
            unsigned inc = s;
#pragma unroll
            for (int off = 1; off < 64; off <<= 1) {
                unsigned o = (unsigned)__shfl_up((int)inc, off, 64);
                if ((tid & 63) >= off) inc += o;
            }
            if ((tid & 63) == 63) swave[tid >> 6] = inc;
            __syncthreads();
            unsigned wbase = 0;
            for (int w = 0; w < (tid >> 6); ++w) wbase += swave[w];
            unsigned run = wbase + inc - s;
#pragma unroll
            for (int j = 0; j < 8; ++j) { sm.c.sprefix[tid * 8 + j] = run; run += vals[j]; }
        }
        __syncthreads();
        // scatter REAL keys only
#pragma unroll
        for (int k = 0; k < 16; ++k) {
            if (kreg[k] != SENT) {
                unsigned dd = ((unsigned)(kreg[k] >> 32) - invLo) >> 3;
                dd = dd > 2047u ? 2047u : dd;
                unsigned pos = atomicAdd(&sm.c.sprefix[dd], 1u);
                sm.c.skey[pos] = kreg[k];
            }
        }
        __syncthreads();
#pragma unroll
        for (int k = 0; k < 16; ++k) {
            unsigned p = tid + k * 256u;
            u64 key = sm.c.skey[p];
            if (key == SENT) continue;
            unsigned dd = ((unsigned)(key >> 32) - invLo) >> 3;
            dd = dd > 2047u ? 2047u : dd;
            unsigned e = sm.c.sprefix[dd];
            unsigned s0 = e - sm.c.shist[dd];
            if (s0 >= (unsigned)CA) continue;            // rank >= s0 >= CA: skip
            int rank = (int)s0;
            for (unsigned q = s0; q < e; ++q) rank += (sm.c.skey[q] < key) ? 1 : 0;
            if (rank < CA) {
                unsigned idx = (unsigned)key;
                float4 b = decode_box(anchor[idx], loc[idx], ih, iw);
                sroi[rank] = b;
                sarea[rank] = (b.z - b.x) * (b.w - b.y);
                if (((b.z - b.x) >= MINSZ) && ((b.w - b.y) >= MINSZ))
                    atomicOr(&svalid[rank >> 5], 1u << (rank & 31));
            }
        }
        __syncthreads();
        // transposed matrix slice: gmatT[gr*CA + jcol] bit c = row 64*gr+c suppresses col jcol
        {
            int task = blockIdx.x * 256 + tid;
            int gr = task / CA;
            int jcol = task - gr * CA;
            int j0 = gr << 6;
            u64 bits = 0;
            if (j0 < jcol) {
                float4 b = sroi[jcol];
                float ab = sarea[jcol];
                int cmax = jcol - j0; cmax = cmax > 64 ? 64 : cmax;
                for (int c = 0; c < cmax; ++c) {
                    int row = j0 + c;
                    float4 r = sroi[row];
                    float yy1 = fmaxf(r.x, b.x);
                    float xx1 = fmaxf(r.y, b.y);
                    float yy2 = fminf(r.z, b.z);
                    float xx2 = fminf(r.w, b.w);
                    float inter = fmaxf(yy2 - yy1, 0.0f) * fmaxf(xx2 - xx1, 0.0f);
                    float iou = inter / (sarea[row] + ab - inter);  // ref op order
                    if (iou > NMS_T) bits |= (1ULL << c);
                }
            }
            gmatT[gr * CA + jcol] = bits;
        }
    }
    // arrive-only done counter; last block continues alone
    __threadfence();
    __syncthreads();
    if (tid == 0) {
        unsigned d = atomicAdd(&cnts[6], 1u);
        sIsLast = (d == GRIDR - 1);
    }
    __syncthreads();
    if (!sIsLast) return;
    __threadfence();   // acquire

    // ---- ballot scan, 4-wide speculative batches (ballots don't waterfall) ----
    int Ceff = CA;     // mainValid guarantees >= CA correctly-ranked candidates
    if (tid < 64 && mainValid) {
        u64 supfut[NG], W[NG], nxtW[NG], kmask[NG];
#pragma unroll
        for (int w = 0; w < NG; ++w) {
            supfut[w] = ~(((u64)svalid[2 * w + 1] << 32) | (u64)svalid[2 * w]);
            kmask[w] = 0ull;
        }
#pragma unroll
        for (int gq = 0; gq < NG; ++gq) W[gq] = gmatT[0 * CA + 64 * gq + tid];
        int nk = 0;
        bool done = false;
#pragma unroll
        for (int g = 0; g < NG; ++g) {
            if (g < NG - 1) {
#pragma unroll
                for (int gq = 0; gq < NG; ++gq) nxtW[gq] = gmatT[(g + 1) * CA + 64 * gq + tid];
            }
            int base = 64 * g;
            if (!done && base < Ceff) {
                u64 bound = (Ceff - base >= 64) ? ~0ull : ((1ull << (Ceff - base)) - 1ull);
                u64 live = ~supfut[g] & bound;
                u64 km = 0;
                while (live) {
                    // extract up to 4 candidate bits (register-only)
                    u64 t = live;
                    int b0 = (int)__builtin_ctzll(t); t &= t - 1;
                    int b1 = t ? (int)__builtin_ctzll(t) : -1; if (t) t &= t - 1;
                    int b2 = t ? (int)__builtin_ctzll(t) : -1; if (t) t &= t - 1;
                    int b3 = t ? (int)__builtin_ctzll(t) : -1;
                    // 4 independent ballots (latencies overlap)
                    u64 m0 = __ballot(((W[g] >> b0) & 1ull) != 0ull);
                    u64 m1 = (b1 >= 0) ? __ballot(((W[g] >> b1) & 1ull) != 0ull) : 0ull;
                    u64 m2 = (b2 >= 0) ? __ballot(((W[g] >> b2) & 1ull) != 0ull) : 0ull;
                    u64 m3 = (b3 >= 0) ? __ballot(((W[g] >> b3) & 1ull) != 0ull) : 0ull;
                    // exact greedy resolve among the batch (ordered, NPOST-trimmed)
                    u64 supx = m0, proc = 1ull << b0;
                    km |= 1ull << b0; ++nk;
                    if (nk == NPOST) done = true;
                    if (!done && b1 >= 0) {
                        proc |= 1ull << b1;
                        if (!((supx >> b1) & 1ull)) {
                            km |= 1ull << b1; supx |= m1; ++nk;
                            if (nk == NPOST) done = true;
                        }
                    }
                    if (!done && b2 >= 0) {
                        proc |= 1ull << b2;
                        if (!((supx >> b2) & 1ull)) {
                            km |= 1ull << b2; supx |= m2; ++nk;
                            if (nk == NPOST) done = true;
                        }
                    }
                    if (!done && b3 >= 0) {
                        proc |= 1ull << b3;
                        if (!((supx >> b3) & 1ull)) {
                            km |= 1ull << b3; supx |= m3; ++nk;
                            if (nk == NPOST) done = true;
                        }
                    }
                    live &= ~(proc | supx);
                    if (done) break;
                }
                kmask[g] = km;
                if (!done && g < NG - 1) {
#pragma unroll
                    for (int gq = 0; gq < NG; ++gq) {
                        if (gq > g) {
                            bool any = (W[gq] & km) != 0ull;
                            supfut[gq] |= __ballot(any);
                        }
                    }
                }
            }
#pragma unroll
            for (int gq = 0; gq < NG; ++gq) W[gq] = nxtW[gq];
        }
        if (tid == 0) {
            snk = nk;
            sflag = (nk < NPOST) ? 1 : 0;
#pragma unroll
            for (int g = 0; g < NG; ++g) skm[g] = kmask[g];
        }
    }
    if (tid == 0 && !mainValid) {
        snk = 0; sflag = 1;
#pragma unroll
        for (int g = 0; g < NG; ++g) skm[g] = 0ull;
    }
    __syncthreads();
    int nk = snk, flag = sflag;
    float4* out4 = (float4*)out;
    if (!flag) {
        int basepc[NG];
        {
            int run = 0;
#pragma unroll
            for (int g = 0; g < NG; ++g) { basepc[g] = run; run += __popcll(skm[g]); }
        }
        int wv = tid >> 6, j = tid & 63;
#pragma unroll
        for (int gg = 0; gg < 2; ++gg) {
            int g = wv + 4 * gg;
            if (g < NG) {
                u64 km = skm[g];
                if ((km >> j) & 1ull) {
                    int rank = basepc[g] + __popcll(km & ((1ull << j) - 1ull));
                    if (rank < NPOST) out4[rank] = sroi[64 * g + j];
                }
            }
        }
        for (int k = nk + tid; k < NPOST; k += 256) out4[k] = make_float4(0.f,0.f,0.f,0.f);
        return;
    }
    // ---------- exact fallback (gated; never taken on sane data) ----------
    __syncthreads();
    for (int b = tid; b < NBIN; b += 256) sm.c.shist[b] = 0;
    __syncthreads();
    for (int i = tid; i < n; i += 256) atomicAdd(&sm.c.shist[sbin_of(score[i])], 1u);
    __syncthreads();
    fastscan2048(sm.c.shist, NPRE, 0, swave, res);
    unsigned b6 = res[0];
    if (tid == 0) sFNW = 0;
    __syncthreads();
    for (int i = tid; i < n; i += 256) {
        float s = score[i];
        if ((unsigned)sbin_of(s) <= b6) {
            float4 r = decode_box(anchor[i], loc[i], ih, iw);
            bool valid = ((r.z - r.x) >= MINSZ) && ((r.w - r.y) >= MINSZ);
            float ms = valid ? s : -__builtin_inff();
            u64 key = ((u64)inv_key(ms) << 32) | (unsigned)i;
            unsigned p = atomicAdd(&sFNW, 1u);
            if (p < CAP6) cand6[p] = key;
        }
    }
    __threadfence();
    __syncthreads();
    unsigned M = sFNW < (unsigned)CAP6 ? sFNW : (unsigned)CAP6;
    for (unsigned i = tid; i < CAP6; i += 256) sm.fb.lk[i] = (i < M) ? cand6[i] : ~0ULL;
    for (int r = tid; r < NPRE; r += 256) order6[r] = 0xFFFFFFFFu;
    __syncthreads();
    for (unsigned c = tid; c < M; c += 256) {
        u64 key = sm.fb.lk[c];
        int rank = 0;
        for (unsigned j = 0; j < M; ++j) rank += (sm.fb.lk[j] < key) ? 1 : 0;
        if (rank < NPRE) order6[rank] = (unsigned)key;
    }
    __syncthreads();
    for (int r = tid; r < NPRE; r += 256) {
        unsigned idx = order6[r];
        float4 b = make_float4(0.f, 0.f, 0.f, 0.f);
        if (idx < (unsigned)n) b = decode_box(anchor[idx], loc[idx], ih, iw);
        roi6[r] = b;
    }
    __syncthreads();
    if (tid < 64) {
        int lane = tid;
        int nk2 = 0;
        for (int i = 0; i < NPRE; i++) {
            float4 b = roi6[i];
            float hs = b.z - b.x, wd = b.w - b.y;
            if (!(hs >= MINSZ && wd >= MINSZ)) continue;
            float ab = hs * wd;
            bool sup = false;
            for (int base = 0; base < nk2 && !sup; base += 64) {
                int t = base + lane;
                bool s = false;
                if (t < nk2) {
                    float yy1 = fmaxf(b.x, sm.fb.y1[t]);
                    float xx1 = fmaxf(b.y, sm.fb.x1[t]);
                    float yy2 = fminf(b.z, sm.fb.y2[t]);
                    float xx2 = fminf(b.w, sm.fb.x2[t]);
                    float inter = fmaxf(yy2 - yy1, 0.0f) * fmaxf(xx2 - xx1, 0.0f);
                    float iou = inter / (sm.fb.ar[t] + ab - inter);
                    s = iou > NMS_T;
                }
                sup = (__ballot(s) != 0ULL);
            }
            if (!sup) {
                if (lane == 0) {
                    sm.fb.y1[nk2] = b.x; sm.fb.x1[nk2] = b.y;
                    sm.fb.y2[nk2] = b.z; sm.fb.x2[nk2] = b.w; sm.fb.ar[nk2] = ab;
                }
                nk2++;
                if (nk2 == NPOST) break;
            }
        }
        for (int k = lane; k < NPOST; k += 64) {
            float4 o = make_float4(0.f, 0.f, 0.f, 0.f);
            if (k < nk2) o = make_float4(sm.fb.y1[k], sm.fb.x1[k], sm.fb.y2[k], sm.fb.x2[k]);
            out4[k] = o;
        }
    }
}

extern "C" void kernel_launch(void* const* d_in, const int* in_sizes, int n_in,
                              void* d_out, int out_size, void* d_ws, size_t ws_size,
                              hipStream_t stream) {
    const float4* loc    = (const float4*)d_in[0];
    const float*  score  = (const float*)d_in[1];
    const float4* anchor = (const float4*)d_in[2];
    const int*    ph     = (const int*)d_in[3];
    const int*    pw     = (const int*)d_in[4];
    int n = in_sizes[1];

    char* ws = (char*)d_ws;
    u64*      cand6  = (u64*)(ws + OFF_CAND6);
    u64*      candA  = (u64*)(ws + OFF_CANDA);
    unsigned* candW  = (unsigned*)(ws + OFF_CANDW);
    unsigned* vW     = (unsigned*)(ws + OFF_VW);
    unsigned* order6 = (unsigned*)(ws + OFF_ORDER6);
    float4*   roi6   = (float4*)(ws + OFF_ROI6);
    u64*      gmatT  = (u64*)(ws + OFF_GMAT);
    unsigned* cnts   = (unsigned*)(ws + OFF_CNT);
    float* out = (float*)d_out;

    k_collect <<<dim3(GRIDC), dim3(256), 0, stream>>>(loc, score, anchor, ph, pw, n,
                                                      candA, candW, vW, cnts);
    k_rankmat <<<dim3(GRIDR), dim3(256), 0, stream>>>(loc, score, anchor, ph, pw, n,
                                                      candA, candW, vW, cand6, cnts,
                                                      gmatT, order6, roi6, out);
}

// Round 23
// 32.041 us; speedup vs baseline: 2.3365x; 1.4535x over previous
//
#include <hip/hip_runtime.h>
#include <stdint.h>

typedef unsigned long long u64;

#define NMS_T 0.7f
#define MINSZ 16.0f
#define NPRE 6000
#define NPOST 300
#define CA   384
#define NG   6          // groups of 64 = CA/64
#define CAP6 8192
#define NBIN 2048
#define GRIDC 128
#define GRIDR 9         // NG*CA/256
#define KCAP 32         // winner slots per collect block
#define MT   (GRIDC*KCAP)   // 4096 candidate slots (sentinel-padded)
#define TFIX 0.9990234375f  // 1 - 1024/2^20; E[winners]=1024 on U[0,1)
#define SENT (~0ULL)        // sentinel; genuine keys can never equal this

// ---- workspace layout (bytes) ----
#define OFF_CAND6  0                          // CAP6*8 (fallback only)
#define OFF_CANDA  (OFF_CAND6 + CAP6*8)       // MT*8 = 32768
#define OFF_CANDW  (OFF_CANDA + MT*8)         // GRIDC*4 (written every call)
#define OFF_VW     (OFF_CANDW + GRIDC*4)      // GRIDC*4 (written every call)
#define OFF_ORDER6 (OFF_VW + GRIDC*4)         // NPRE*4  (fallback)
#define OFF_ROI6   (OFF_ORDER6 + NPRE*4)      // NPRE*16 (fallback)
#define OFF_GMAT   (OFF_ROI6 + NPRE*16)       // NG*CA*8 transposed gmatT[gr*CA+col]
#define OFF_CNT    (OFF_GMAT + NG*CA*8)       // 32: [6]=done2 (zeroed by k_collect blk0)

__device__ __forceinline__ unsigned inv_key(float s) {
    unsigned u = __float_as_uint(s);
    unsigned k = (u & 0x80000000u) ? ~u : (u | 0x80000000u);
    return ~k;   // ascending inv == descending score
}

__device__ __forceinline__ float4 decode_box(const float4 a, const float4 l,
                                             float ih, float iw) {
    float h  = a.z - a.x;
    float w  = a.w - a.y;
    float cy = a.x + 0.5f * h;
    float cx = a.y + 0.5f * w;
    float ncy = l.x * h + cy;
    float ncx = l.y * w + cx;
    float nh  = expf(l.z) * h;
    float nw  = expf(l.w) * w;
    float y1 = fminf(fmaxf(ncy - 0.5f * nh, 0.0f), ih);
    float x1 = fminf(fmaxf(ncx - 0.5f * nw, 0.0f), iw);
    float y2 = fminf(fmaxf(ncy + 0.5f * nh, 0.0f), ih);
    float x2 = fminf(fmaxf(ncx + 0.5f * nw, 0.0f), iw);
    return make_float4(y1, x1, y2, x2);
}

__device__ __forceinline__ int sbin_of(float s) {
    int b = (int)(s * 2048.0f);
    b = b < 0 ? 0 : (b > 2047 ? 2047 : b);
    return 2047 - b;           // ascending = descending score
}

// fast block scan of 2048-bin histogram (2 barriers): bins containing ranks t0/t1
__device__ void fastscan2048(const unsigned* __restrict__ h, unsigned t0, unsigned t1,
                             unsigned* swave, unsigned* res) {
    int t = threadIdx.x;
    unsigned vals[8], s = 0;
#pragma unroll
    for (int j = 0; j < 8; ++j) { vals[j] = h[t * 8 + j]; s += vals[j]; }
    unsigned inc = s;
#pragma unroll
    for (int off = 1; off < 64; off <<= 1) {
        unsigned o = (unsigned)__shfl_up((int)inc, off, 64);
        if ((t & 63) >= off) inc += o;
    }
    if ((t & 63) == 63) swave[t >> 6] = inc;
    __syncthreads();
    unsigned wbase = 0;
    for (int w = 0; w < (t >> 6); ++w) wbase += swave[w];
    unsigned run = wbase + inc - s;
#pragma unroll
    for (int j = 0; j < 8; ++j) {
        unsigned c = vals[j];
        if (run < t0 && run + c >= t0) { res[0] = t * 8 + j; res[1] = run; }
        if (t1 && run < t1 && run + c >= t1) { res[2] = t * 8 + j; res[3] = run; }
        run += c;
    }
    __syncthreads();
}

// ---- 1: fixed-threshold single-pass collect; per-block slots (no global atomics) ----
__global__ void __launch_bounds__(256) k_collect(
        const float4* __restrict__ loc, const float* __restrict__ score,
        const float4* __restrict__ anchor, const int* __restrict__ ph,
        const int* __restrict__ pw, int n,
        u64* __restrict__ candA, unsigned* __restrict__ candW,
        unsigned* __restrict__ vW, unsigned* __restrict__ cnts) {
    __shared__ u64 win[KCAP];
    __shared__ unsigned sNW, sVW;
    const int tid = threadIdx.x, bid = blockIdx.x;
    if (tid == 0) { sNW = 0; sVW = 0; }
    if (bid == 0 && tid == 0) cnts[6] = 0;    // done-counter for k_rankmat
    __syncthreads();
    const int gtid = bid * 256 + tid;
    const int T = GRIDC * 256;
    const float ih = (float)ph[0], iw = (float)pw[0];
    const int n4 = n >> 2, ntail = n4 << 2;
    const float4* s4 = (const float4*)score;
    for (int idx0 = gtid; idx0 < n4; idx0 += T * 8) {
        float4 v[8]; int ok[8];
#pragma unroll
        for (int k = 0; k < 8; ++k) {
            int idx = idx0 + k * T;
            ok[k] = idx < n4;
            v[k] = ok[k] ? s4[idx] : make_float4(0.f, 0.f, 0.f, 0.f);
        }
#pragma unroll
        for (int k = 0; k < 8; ++k) if (ok[k]) {
            float sc[4] = {v[k].x, v[k].y, v[k].z, v[k].w};
            int ib = (idx0 + k * T) << 2;
#pragma unroll
            for (int c = 0; c < 4; ++c) {
                if (sc[c] > TFIX) {
                    int i = ib + c;
                    float4 r = decode_box(anchor[i], loc[i], ih, iw);
                    bool valid = ((r.z - r.x) >= MINSZ) && ((r.w - r.y) >= MINSZ);
                    float ms = valid ? sc[c] : -__builtin_inff();
                    u64 key = ((u64)inv_key(ms) << 32) | (unsigned)i;
                    unsigned p = atomicAdd(&sNW, 1u);
                    if (p < KCAP) win[p] = key;
                    if (valid) atomicAdd(&sVW, 1u);
                }
            }
        }
    }
    for (int i = ntail + gtid; i < n; i += T) {
        float s = score[i];
        if (s > TFIX) {
            float4 r = decode_box(anchor[i], loc[i], ih, iw);
            bool valid = ((r.z - r.x) >= MINSZ) && ((r.w - r.y) >= MINSZ);
            float ms = valid ? s : -__builtin_inff();
            u64 key = ((u64)inv_key(ms) << 32) | (unsigned)i;
            unsigned p = atomicAdd(&sNW, 1u);
            if (p < KCAP) win[p] = key;
            if (valid) atomicAdd(&sVW, 1u);
        }
    }
    __syncthreads();
    unsigned NW = sNW;
    unsigned NWc = NW < KCAP ? NW : KCAP;
    for (int i = tid; i < KCAP; i += 256)
        candA[bid * KCAP + i] = (i < (int)NWc) ? win[i] : SENT;
    if (tid == 0) { candW[bid] = NW; vW[bid] = sVW; }   // written EVERY call
}

struct SmC {
    u64 skey[MT];            // 32 KB
    unsigned shist[NBIN];    // 8 KB
    unsigned sprefix[NBIN];  // 8 KB
};
struct SmFb {
    u64   lk[CAP6];          // 64 KB
    float y1[NPOST], x1[NPOST], y2[NPOST], x2[NPOST], ar[NPOST];
};
union SmR { SmC c; SmFb fb; };

// ---- 2: 9 blocks: counting-sort rank -> decode -> matrix -> fixed-point NMS ----
__global__ void __launch_bounds__(256) k_rankmat(
        const float4* __restrict__ loc, const float* __restrict__ score,
        const float4* __restrict__ anchor, const int* __restrict__ ph,
        const int* __restrict__ pw, int n,
        const u64* __restrict__ candA, const unsigned* __restrict__ candW,
        const unsigned* __restrict__ vW, u64* __restrict__ cand6,
        unsigned* __restrict__ cnts, u64* __restrict__ gmatT,
        unsigned* __restrict__ order6, float4* __restrict__ roi6,
        float* __restrict__ out) {
    __shared__ SmR sm;
    __shared__ float4 sroi[CA];
    __shared__ float  sarea[CA];
    __shared__ unsigned svalid[CA / 32];
    __shared__ unsigned swave[8], res[8];
    __shared__ unsigned sInvLo, sVV, sOvf, sFNW;
    __shared__ int sIsLast;
    __shared__ u64 skm[NG];
    __shared__ int snk, sflag;
    int tid = threadIdx.x;
    float ih = (float)ph[0], iw = (float)pw[0];

    if (tid == 0) { sVV = 0; sOvf = 0; sInvLo = 0xFFFFFFFFu; }
    __syncthreads();
    // wave-reduced guard accumulation (2 LDS atomics total, not 128)
    {
        unsigned vv = 0, ovf = 0;
        if (tid < GRIDC) {
            unsigned w = candW[tid];
            ovf = (w > KCAP) ? 1u : 0u;
            vv = vW[tid];
        }
#pragma unroll
        for (int off = 32; off; off >>= 1) {
            vv  += (unsigned)__shfl_down((int)vv, off, 64);
            ovf |= (unsigned)__shfl_down((int)ovf, off, 64);
        }
        if (tid < GRIDC && (tid & 63) == 0) {
            atomicAdd(&sVV, vv);
            if (ovf) atomicOr(&sOvf, 1u);
        }
    }
    __syncthreads();
    const bool mainValid = (sOvf == 0u) && (sVV >= (unsigned)CA);

    if (mainValid) {
        for (int b = tid; b < NBIN; b += 256) sm.c.shist[b] = 0;
        for (int r = tid; r < CA; r += 256) { sroi[r] = make_float4(0.f,0.f,0.f,0.f); sarea[r] = 0.f; }
        if (tid < CA / 32) svalid[tid] = 0;
        u64 kreg[16];
#pragma unroll
        for (int k = 0; k < 16; ++k) {
            kreg[k] = candA[tid + k * 256];
            sm.c.skey[tid + k * 256] = SENT;     // pre-init; unscattered slots stay sentinel
        }
        unsigned mymin = 0xFFFFFFFFu;
#pragma unroll
        for (int k = 0; k < 16; ++k) {
            if (kreg[k] != SENT) {
                unsigned hi = (unsigned)(kreg[k] >> 32);
                mymin = mymin < hi ? mymin : hi;
            }
        }
#pragma unroll
        for (int off = 32; off; off >>= 1) {
            unsigned o = (unsigned)__shfl_down((int)mymin, off, 64);
            mymin = mymin < o ? mymin : o;
        }
        if ((tid & 63) == 0) atomicMin(&sInvLo, mymin);
        __syncthreads();
        unsigned invLo = sInvLo;
        // histogram REAL keys only (sentinels skipped -> no same-bin contention)
#pragma unroll
        for (int k = 0; k < 16; ++k) {
            if (kreg[k] != SENT) {
                unsigned dd = ((unsigned)(kreg[k] >> 32) - invLo) >> 3;
                atomicAdd(&sm.c.shist[dd > 2047u ? 2047u : dd], 1u);
            }
        }
        __syncthreads();
        {   // fast exclusive prefix into sprefix
            unsigned vals[8], s = 0;
#pragma unroll
            for (int j = 0; j < 8; ++j) { vals[j] = sm.c.shist[tid * 8 + j]; s += vals[j]; }
            unsigned inc = s;
#pragma unroll
            for (int off = 1; off < 64; off <<= 1) {
                unsigned o = (unsigned)__shfl_up((int)inc, off, 64);
                if ((tid & 63) >= off) inc += o;
            }
            if ((tid & 63) == 63) swave[tid >> 6] = inc;
            __syncthreads();
            unsigned wbase = 0;
            for (int w = 0; w < (tid >> 6); ++w) wbase += swave[w];
            unsigned run = wbase + inc - s;
#pragma unroll
            for (int j = 0; j < 8; ++j) { sm.c.sprefix[tid * 8 + j] = run; run += vals[j]; }
        }
        __syncthreads();
        // scatter REAL keys only
#pragma unroll
        for (int k = 0; k < 16; ++k) {
            if (kreg[k] != SENT) {
                unsigned dd = ((unsigned)(kreg[k] >> 32) - invLo) >> 3;
                dd = dd > 2047u ? 2047u : dd;
                unsigned pos = atomicAdd(&sm.c.sprefix[dd], 1u);
                sm.c.skey[pos] = kreg[k];
            }
        }
        __syncthreads();
#pragma unroll
        for (int k = 0; k < 16; ++k) {
            unsigned p = tid + k * 256u;
            u64 key = sm.c.skey[p];
            if (key == SENT) continue;
            unsigned dd = ((unsigned)(key >> 32) - invLo) >> 3;
            dd = dd > 2047u ? 2047u : dd;
            unsigned e = sm.c.sprefix[dd];
            unsigned s0 = e - sm.c.shist[dd];
            if (s0 >= (unsigned)CA) continue;            // rank >= s0 >= CA: skip
            int rank = (int)s0;
            for (unsigned q = s0; q < e; ++q) rank += (sm.c.skey[q] < key) ? 1 : 0;
            if (rank < CA) {
                unsigned idx = (unsigned)key;
                float4 b = decode_box(anchor[idx], loc[idx], ih, iw);
                sroi[rank] = b;
                sarea[rank] = (b.z - b.x) * (b.w - b.y);
                if (((b.z - b.x) >= MINSZ) && ((b.w - b.y) >= MINSZ))
                    atomicOr(&svalid[rank >> 5], 1u << (rank & 31));
            }
        }
        __syncthreads();
        // transposed matrix slice: gmatT[gr*CA + jcol] bit c = row 64*gr+c suppresses col jcol
        {
            int task = blockIdx.x * 256 + tid;
            int gr = task / CA;
            int jcol = task - gr * CA;
            int j0 = gr << 6;
            u64 bits = 0;
            if (j0 < jcol) {
                float4 b = sroi[jcol];
                float ab = sarea[jcol];
                int cmax = jcol - j0; cmax = cmax > 64 ? 64 : cmax;
                for (int c = 0; c < cmax; ++c) {
                    int row = j0 + c;
                    float4 r = sroi[row];
                    float yy1 = fmaxf(r.x, b.x);
                    float xx1 = fmaxf(r.y, b.y);
                    float yy2 = fminf(r.z, b.z);
                    float xx2 = fminf(r.w, b.w);
                    float inter = fmaxf(yy2 - yy1, 0.0f) * fmaxf(xx2 - xx1, 0.0f);
                    float iou = inter / (sarea[row] + ab - inter);  // ref op order
                    if (iou > NMS_T) bits |= (1ULL << c);
                }
            }
            gmatT[gr * CA + jcol] = bits;
        }
    }
    // arrive-only done counter; last block continues alone
    __threadfence();
    __syncthreads();
    if (tid == 0) {
        unsigned d = atomicAdd(&cnts[6], 1u);
        sIsLast = (d == GRIDR - 1);
    }
    __syncthreads();
    if (!sIsLast) return;
    __threadfence();   // acquire

    // ---- fixed-point NMS: O(#suppressed) rounds; exact (confirmed-prefix argument) ----
    if (tid < 64 && mainValid) {
        // full 6x6 block of the transposed matrix into registers (g>gq rows are zero)
        u64 M[NG][NG];
#pragma unroll
        for (int gq = 0; gq < NG; ++gq)
#pragma unroll
            for (int g = 0; g < NG; ++g)
                M[gq][g] = gmatT[g * CA + 64 * gq + tid];
        u64 inval[NG];
#pragma unroll
        for (int g = 0; g < NG; ++g)
            inval[g] = ~(((u64)svalid[2 * g + 1] << 32) | (u64)svalid[2 * g]);

        u64 K[NG];
        int nk = 0;
        // K = Phi(empty): prefix-NPOST of valid
        {
            int run = 0;
#pragma unroll
            for (int g = 0; g < NG; ++g) {
                u64 m = ~inval[g];
                int c = __popcll(m);
                if (run + c <= NPOST) { K[g] = m; run += c; }
                else {
                    int need = NPOST - run;
                    u64 r2 = 0;
                    for (int t = 0; t < need; ++t) { int b = (int)__builtin_ctzll(m); r2 |= 1ull << b; m &= m - 1; }
                    K[g] = r2; run = NPOST;
                }
            }
            nk = run;
        }
        for (int it = 0; it <= CA; ++it) {
            u64 supp[NG];
#pragma unroll
            for (int gq = 0; gq < NG; ++gq) {
                u64 acc = 0;
#pragma unroll
                for (int g = 0; g < NG; ++g) acc |= M[gq][g] & K[g];
                supp[gq] = __ballot(acc != 0ull);
            }
            u64 Kn[NG];
            int run = 0;
#pragma unroll
            for (int g = 0; g < NG; ++g) {
                u64 m = ~supp[g] & ~inval[g];
                int c = __popcll(m);
                if (run + c <= NPOST) { Kn[g] = m; run += c; }
                else {
                    int need = NPOST - run;
                    u64 r2 = 0;
                    for (int t = 0; t < need; ++t) { int b = (int)__builtin_ctzll(m); r2 |= 1ull << b; m &= m - 1; }
                    Kn[g] = r2; run = NPOST;
                }
            }
            bool same = true;
#pragma unroll
            for (int g = 0; g < NG; ++g) same = same && (Kn[g] == K[g]);
#pragma unroll
            for (int g = 0; g < NG; ++g) K[g] = Kn[g];
            nk = run;
            if (same) break;
        }
        if (tid == 0) {
            snk = nk;
            sflag = (nk < NPOST) ? 1 : 0;
#pragma unroll
            for (int g = 0; g < NG; ++g) skm[g] = K[g];
        }
    }
    if (tid == 0 && !mainValid) {
        snk = 0; sflag = 1;
#pragma unroll
        for (int g = 0; g < NG; ++g) skm[g] = 0ull;
    }
    __syncthreads();
    int nk = snk, flag = sflag;
    float4* out4 = (float4*)out;
    if (!flag) {
        int basepc[NG];
        {
            int run = 0;
#pragma unroll
            for (int g = 0; g < NG; ++g) { basepc[g] = run; run += __popcll(skm[g]); }
        }
        int wv = tid >> 6, j = tid & 63;
#pragma unroll
        for (int gg = 0; gg < 2; ++gg) {
            int g = wv + 4 * gg;
            if (g < NG) {
                u64 km = skm[g];
                if ((km >> j) & 1ull) {
                    int rank = basepc[g] + __popcll(km & ((1ull << j) - 1ull));
                    if (rank < NPOST) out4[rank] = sroi[64 * g + j];
                }
            }
        }
        for (int k = nk + tid; k < NPOST; k += 256) out4[k] = make_float4(0.f,0.f,0.f,0.f);
        return;
    }
    // ---------- exact fallback (gated; never taken on sane data) ----------
    __syncthreads();
    for (int b = tid; b < NBIN; b += 256) sm.c.shist[b] = 0;
    __syncthreads();
    for (int i = tid; i < n; i += 256) atomicAdd(&sm.c.shist[sbin_of(score[i])], 1u);
    __syncthreads();
    fastscan2048(sm.c.shist, NPRE, 0, swave, res);
    unsigned b6 = res[0];
    if (tid == 0) sFNW = 0;
    __syncthreads();
    for (int i = tid; i < n; i += 256) {
        float s = score[i];
        if ((unsigned)sbin_of(s) <= b6) {
            float4 r = decode_box(anchor[i], loc[i], ih, iw);
            bool valid = ((r.z - r.x) >= MINSZ) && ((r.w - r.y) >= MINSZ);
            float ms = valid ? s : -__builtin_inff();
            u64 key = ((u64)inv_key(ms) << 32) | (unsigned)i;
            unsigned p = atomicAdd(&sFNW, 1u);
            if (p < CAP6) cand6[p] = key;
        }
    }
    __threadfence();
    __syncthreads();
    unsigned M2 = sFNW < (unsigned)CAP6 ? sFNW : (unsigned)CAP6;
    for (unsigned i = tid; i < CAP6; i += 256) sm.fb.lk[i] = (i < M2) ? cand6[i] : ~0ULL;
    for (int r = tid; r < NPRE; r += 256) order6[r] = 0xFFFFFFFFu;
    __syncthreads();
    for (unsigned c = tid; c < M2; c += 256) {
        u64 key = sm.fb.lk[c];
        int rank = 0;
        for (unsigned j = 0; j < M2; ++j) rank += (sm.fb.lk[j] < key) ? 1 : 0;
        if (rank < NPRE) order6[rank] = (unsigned)key;
    }
    __syncthreads();
    for (int r = tid; r < NPRE; r += 256) {
        unsigned idx = order6[r];
        float4 b = make_float4(0.f, 0.f, 0.f, 0.f);
        if (idx < (unsigned)n) b = decode_box(anchor[idx], loc[idx], ih, iw);
        roi6[r] = b;
    }
    __syncthreads();
    if (tid < 64) {
        int lane = tid;
        int nk2 = 0;
        for (int i = 0; i < NPRE; i++) {
            float4 b = roi6[i];
            float hs = b.z - b.x, wd = b.w - b.y;
            if (!(hs >= MINSZ && wd >= MINSZ)) continue;
            float ab = hs * wd;
            bool sup = false;
            for (int base = 0; base < nk2 && !sup; base += 64) {
                int t = base + lane;
                bool s = false;
                if (t < nk2) {
                    float yy1 = fmaxf(b.x, sm.fb.y1[t]);
                    float xx1 = fmaxf(b.y, sm.fb.x1[t]);
                    float yy2 = fminf(b.z, sm.fb.y2[t]);
                    float xx2 = fminf(b.w, sm.fb.x2[t]);
                    float inter = fmaxf(yy2 - yy1, 0.0f) * fmaxf(xx2 - xx1, 0.0f);
                    float iou = inter / (sm.fb.ar[t] + ab - inter);
                    s = iou > NMS_T;
                }
                sup = (__ballot(s) != 0ULL);
            }
            if (!sup) {
                if (lane == 0) {
                    sm.fb.y1[nk2] = b.x; sm.fb.x1[nk2] = b.y;
                    sm.fb.y2[nk2] = b.z; sm.fb.x2[nk2] = b.w; sm.fb.ar[nk2] = ab;
                }
                nk2++;
                if (nk2 == NPOST) break;
            }
        }
        for (int k = lane; k < NPOST; k += 64) {
            float4 o = make_float4(0.f, 0.f, 0.f, 0.f);
            if (k < nk2) o = make_float4(sm.fb.y1[k], sm.fb.x1[k], sm.fb.y2[k], sm.fb.x2[k]);
            out4[k] = o;
        }
    }
}

extern "C" void kernel_launch(void* const* d_in, const int* in_sizes, int n_in,
                              void* d_out, int out_size, void* d_ws, size_t ws_size,
                              hipStream_t stream) {
    const float4* loc    = (const float4*)d_in[0];
    const float*  score  = (const float*)d_in[1];
    const float4* anchor = (const float4*)d_in[2];
    const int*    ph     = (const int*)d_in[3];
    const int*    pw     = (const int*)d_in[4];
    int n = in_sizes[1];

    char* ws = (char*)d_ws;
    u64*      cand6  = (u64*)(ws + OFF_CAND6);
    u64*      candA  = (u64*)(ws + OFF_CANDA);
    unsigned* candW  = (unsigned*)(ws + OFF_CANDW);
    unsigned* vW     = (unsigned*)(ws + OFF_VW);
    unsigned* order6 = (unsigned*)(ws + OFF_ORDER6);
    float4*   roi6   = (float4*)(ws + OFF_ROI6);
    u64*      gmatT  = (u64*)(ws + OFF_GMAT);
    unsigned* cnts   = (unsigned*)(ws + OFF_CNT);
    float* out = (float*)d_out;

    k_collect <<<dim3(GRIDC), dim3(256), 0, stream>>>(loc, score, anchor, ph, pw, n,
                                                      candA, candW, vW, cnts);
    k_rankmat <<<dim3(GRIDR), dim3(256), 0, stream>>>(loc, score, anchor, ph, pw, n,
                                                      candA, candW, vW, cand6, cnts,
                                                      gmatT, order6, roi6, out);
}

// Round 24
// 31.796 us; speedup vs baseline: 2.3545x; 1.0077x over previous
//
#include <hip/hip_runtime.h>
#include <stdint.h>

typedef unsigned long long u64;

#define NMS_T 0.7f
#define MINSZ 16.0f
#define NPRE 6000
#define NPOST 300
#define CA   384
#define NG   6          // groups of 64 = CA/64
#define CAP6 8192
#define NBIN 2048
#define GRIDC 256
#define GRIDR 9         // NG*CA/256
#define KCAP 16         // winner slots per collect block
#define MT   (GRIDC*KCAP)   // 4096 candidate slots (sentinel-padded)
#define TFIX 0.9990234375f  // 1 - 1024/2^20; E[winners]=1024 on U[0,1)
#define SENT (~0ULL)        // sentinel; genuine keys can never equal this

// ---- workspace layout (bytes) ----
#define OFF_CAND6  0                          // CAP6*8 (fallback only)
#define OFF_CANDA  (OFF_CAND6 + CAP6*8)       // MT*8 = 32768
#define OFF_CANDW  (OFF_CANDA + MT*8)         // GRIDC*4 (written every call)
#define OFF_VW     (OFF_CANDW + GRIDC*4)      // GRIDC*4 (written every call)
#define OFF_ORDER6 (OFF_VW + GRIDC*4)         // NPRE*4  (fallback)
#define OFF_ROI6   (OFF_ORDER6 + NPRE*4)      // NPRE*16 (fallback)
#define OFF_GMAT   (OFF_ROI6 + NPRE*16)       // NG*CA*8 transposed gmatT[gr*CA+col]
#define OFF_CNT    (OFF_GMAT + NG*CA*8)       // 32: [6]=done2 (zeroed by k_collect blk0)

__device__ __forceinline__ unsigned inv_key(float s) {
    unsigned u = __float_as_uint(s);
    unsigned k = (u & 0x80000000u) ? ~u : (u | 0x80000000u);
    return ~k;   // ascending inv == descending score
}

__device__ __forceinline__ float4 decode_box(const float4 a, const float4 l,
                                             float ih, float iw) {
    float h  = a.z - a.x;
    float w  = a.w - a.y;
    float cy = a.x + 0.5f * h;
    float cx = a.y + 0.5f * w;
    float ncy = l.x * h + cy;
    float ncx = l.y * w + cx;
    float nh  = expf(l.z) * h;
    float nw  = expf(l.w) * w;
    float y1 = fminf(fmaxf(ncy - 0.5f * nh, 0.0f), ih);
    float x1 = fminf(fmaxf(ncx - 0.5f * nw, 0.0f), iw);
    float y2 = fminf(fmaxf(ncy + 0.5f * nh, 0.0f), ih);
    float x2 = fminf(fmaxf(ncx + 0.5f * nw, 0.0f), iw);
    return make_float4(y1, x1, y2, x2);
}

__device__ __forceinline__ int sbin_of(float s) {
    int b = (int)(s * 2048.0f);
    b = b < 0 ? 0 : (b > 2047 ? 2047 : b);
    return 2047 - b;           // ascending = descending score
}

// fast block scan of 2048-bin histogram (2 barriers): bins containing ranks t0/t1
__device__ void fastscan2048(const unsigned* __restrict__ h, unsigned t0, unsigned t1,
                             unsigned* swave, unsigned* res) {
    int t = threadIdx.x;
    unsigned vals[8], s = 0;
#pragma unroll
    for (int j = 0; j < 8; ++j) { vals[j] = h[t * 8 + j]; s += vals[j]; }
    unsigned inc = s;
#pragma unroll
    for (int off = 1; off < 64; off <<= 1) {
        unsigned o = (unsigned)__shfl_up((int)inc, off, 64);
        if ((t & 63) >= off) inc += o;
    }
    if ((t & 63) == 63) swave[t >> 6] = inc;
    __syncthreads();
    unsigned wbase = 0;
    for (int w = 0; w < (t >> 6); ++w) wbase += swave[w];
    unsigned run = wbase + inc - s;
#pragma unroll
    for (int j = 0; j < 8; ++j) {
        unsigned c = vals[j];
        if (run < t0 && run + c >= t0) { res[0] = t * 8 + j; res[1] = run; }
        if (t1 && run < t1 && run + c >= t1) { res[2] = t * 8 + j; res[3] = run; }
        run += c;
    }
    __syncthreads();
}

// ---- 1: fixed-threshold single-pass collect; per-block slots (no global atomics) ----
__global__ void __launch_bounds__(256) k_collect(
        const float4* __restrict__ loc, const float* __restrict__ score,
        const float4* __restrict__ anchor, const int* __restrict__ ph,
        const int* __restrict__ pw, int n,
        u64* __restrict__ candA, unsigned* __restrict__ candW,
        unsigned* __restrict__ vW, unsigned* __restrict__ cnts) {
    __shared__ u64 win[KCAP];
    __shared__ unsigned sNW, sVW;
    const int tid = threadIdx.x, bid = blockIdx.x;
    if (tid == 0) { sNW = 0; sVW = 0; }
    if (bid == 0 && tid == 0) cnts[6] = 0;    // done-counter for k_rankmat
    __syncthreads();
    const int gtid = bid * 256 + tid;
    const int T = GRIDC * 256;
    const float ih = (float)ph[0], iw = (float)pw[0];
    const int n4 = n >> 2, ntail = n4 << 2;
    const float4* s4 = (const float4*)score;
    for (int idx0 = gtid; idx0 < n4; idx0 += T * 8) {
        float4 v[8]; int ok[8];
#pragma unroll
        for (int k = 0; k < 8; ++k) {
            int idx = idx0 + k * T;
            ok[k] = idx < n4;
            v[k] = ok[k] ? s4[idx] : make_float4(0.f, 0.f, 0.f, 0.f);
        }
#pragma unroll
        for (int k = 0; k < 8; ++k) if (ok[k]) {
            float sc[4] = {v[k].x, v[k].y, v[k].z, v[k].w};
            int ib = (idx0 + k * T) << 2;
#pragma unroll
            for (int c = 0; c < 4; ++c) {
                if (sc[c] > TFIX) {
                    int i = ib + c;
                    float4 r = decode_box(anchor[i], loc[i], ih, iw);
                    bool valid = ((r.z - r.x) >= MINSZ) && ((r.w - r.y) >= MINSZ);
                    float ms = valid ? sc[c] : -__builtin_inff();
                    u64 key = ((u64)inv_key(ms) << 32) | (unsigned)i;
                    unsigned p = atomicAdd(&sNW, 1u);
                    if (p < KCAP) win[p] = key;
                    if (valid) atomicAdd(&sVW, 1u);
                }
            }
        }
    }
    for (int i = ntail + gtid; i < n; i += T) {
        float s = score[i];
        if (s > TFIX) {
            float4 r = decode_box(anchor[i], loc[i], ih, iw);
            bool valid = ((r.z - r.x) >= MINSZ) && ((r.w - r.y) >= MINSZ);
            float ms = valid ? s : -__builtin_inff();
            u64 key = ((u64)inv_key(ms) << 32) | (unsigned)i;
            unsigned p = atomicAdd(&sNW, 1u);
            if (p < KCAP) win[p] = key;
            if (valid) atomicAdd(&sVW, 1u);
        }
    }
    __syncthreads();
    unsigned NW = sNW;
    unsigned NWc = NW < KCAP ? NW : KCAP;
    for (int i = tid; i < KCAP; i += 256)
        candA[bid * KCAP + i] = (i < (int)NWc) ? win[i] : SENT;
    if (tid == 0) { candW[bid] = NW; vW[bid] = sVW; }   // written EVERY call
}

struct SmC {
    u64 skey[MT];            // 32 KB
    unsigned shist[NBIN];    // 8 KB
    unsigned sprefix[NBIN];  // 8 KB
};
struct SmFb {
    u64   lk[CAP6];          // 64 KB
    float y1[NPOST], x1[NPOST], y2[NPOST], x2[NPOST], ar[NPOST];
};
union SmR { SmC c; SmFb fb; };

// ---- 2: 9 blocks: counting-sort rank -> decode -> matrix -> fixed-point NMS ----
__global__ void __launch_bounds__(256) k_rankmat(
        const float4* __restrict__ loc, const float* __restrict__ score,
        const float4* __restrict__ anchor, const int* __restrict__ ph,
        const int* __restrict__ pw, int n,
        const u64* __restrict__ candA, const unsigned* __restrict__ candW,
        const unsigned* __restrict__ vW, u64* __restrict__ cand6,
        unsigned* __restrict__ cnts, u64* __restrict__ gmatT,
        unsigned* __restrict__ order6, float4* __restrict__ roi6,
        float* __restrict__ out) {
    __shared__ SmR sm;
    __shared__ float4 sroi[CA];
    __shared__ float  sarea[CA];
    __shared__ unsigned svalid[CA / 32];
    __shared__ unsigned swave[8], res[8];
    __shared__ unsigned sInvLo, sVV, sOvf, sFNW;
    __shared__ int sIsLast;
    __shared__ u64 skm[NG];
    __shared__ int snk, sflag;
    int tid = threadIdx.x;
    float ih = (float)ph[0], iw = (float)pw[0];

    if (tid == 0) { sVV = 0; sOvf = 0; sInvLo = 0xFFFFFFFFu; }
    __syncthreads();
    // wave-reduced guard accumulation (8 LDS atomics total, not 256)
    {
        unsigned vv = 0, ovf = 0;
        if (tid < GRIDC) {
            unsigned w = candW[tid];
            ovf = (w > KCAP) ? 1u : 0u;
            vv = vW[tid];
        }
#pragma unroll
        for (int off = 32; off; off >>= 1) {
            vv  += (unsigned)__shfl_down((int)vv, off, 64);
            ovf |= (unsigned)__shfl_down((int)ovf, off, 64);
        }
        if (tid < GRIDC && (tid & 63) == 0) {
            atomicAdd(&sVV, vv);
            if (ovf) atomicOr(&sOvf, 1u);
        }
    }
    __syncthreads();
    const bool mainValid = (sOvf == 0u) && (sVV >= (unsigned)CA);

    if (mainValid) {
        for (int b = tid; b < NBIN; b += 256) sm.c.shist[b] = 0;
        for (int r = tid; r < CA; r += 256) { sroi[r] = make_float4(0.f,0.f,0.f,0.f); sarea[r] = 0.f; }
        if (tid < CA / 32) svalid[tid] = 0;
        u64 kreg[16];
#pragma unroll
        for (int k = 0; k < 16; ++k) {
            kreg[k] = candA[tid + k * 256];
            sm.c.skey[tid + k * 256] = SENT;     // pre-init; unscattered slots stay sentinel
        }
        unsigned mymin = 0xFFFFFFFFu;
#pragma unroll
        for (int k = 0; k < 16; ++k) {
            if (kreg[k] != SENT) {
                unsigned hi = (unsigned)(kreg[k] >> 32);
                mymin = mymin < hi ? mymin : hi;
            }
        }
#pragma unroll
        for (int off = 32; off; off >>= 1) {
            unsigned o = (unsigned)__shfl_down((int)mymin, off, 64);
            mymin = mymin < o ? mymin : o;
        }
        if ((tid & 63) == 0) atomicMin(&sInvLo, mymin);
        __syncthreads();
        unsigned invLo = sInvLo;
        // histogram REAL keys only (sentinels skipped -> no same-bin contention)
#pragma unroll
        for (int k = 0; k < 16; ++k) {
            if (kreg[k] != SENT) {
                unsigned dd = ((unsigned)(kreg[k] >> 32) - invLo) >> 3;
                atomicAdd(&sm.c.shist[dd > 2047u ? 2047u : dd], 1u);
            }
        }
        __syncthreads();
        {   // fast exclusive prefix into sprefix
            unsigned vals[8], s = 0;
#pragma unroll
            for (int j = 0; j < 8; ++j) { vals[j] = sm.c.shist[tid * 8 + j]; s += vals[j]; }
            unsigned inc = s;
#pragma unroll
            for (int off = 1; off < 64; off <<= 1) {
                unsigned o = (unsigned)__shfl_up((int)inc, off, 64);
                if ((tid & 63) >= off) inc += o;
            }
            if ((tid & 63) == 63) swave[tid >> 6] = inc;
            __syncthreads();
            unsigned wbase = 0;
            for (int w = 0; w < (tid >> 6); ++w) wbase += swave[w];
            unsigned run = wbase + inc - s;
#pragma unroll
            for (int j = 0; j < 8; ++j) { sm.c.sprefix[tid * 8 + j] = run; run += vals[j]; }
        }
        __syncthreads();
        // scatter REAL keys only
#pragma unroll
        for (int k = 0; k < 16; ++k) {
            if (kreg[k] != SENT) {
                unsigned dd = ((unsigned)(kreg[k] >> 32) - invLo) >> 3;
                dd = dd > 2047u ? 2047u : dd;
                unsigned pos = atomicAdd(&sm.c.sprefix[dd], 1u);
                sm.c.skey[pos] = kreg[k];
            }
        }
        __syncthreads();
#pragma unroll
        for (int k = 0; k < 16; ++k) {
            unsigned p = tid + k * 256u;
            u64 key = sm.c.skey[p];
            if (key == SENT) continue;
            unsigned dd = ((unsigned)(key >> 32) - invLo) >> 3;
            dd = dd > 2047u ? 2047u : dd;
            unsigned e = sm.c.sprefix[dd];
            unsigned s0 = e - sm.c.shist[dd];
            if (s0 >= (unsigned)CA) continue;            // rank >= s0 >= CA: skip
            int rank = (int)s0;
            for (unsigned q = s0; q < e; ++q) rank += (sm.c.skey[q] < key) ? 1 : 0;
            if (rank < CA) {
                unsigned idx = (unsigned)key;
                float4 b = decode_box(anchor[idx], loc[idx], ih, iw);
                sroi[rank] = b;
                sarea[rank] = (b.z - b.x) * (b.w - b.y);
                if (((b.z - b.x) >= MINSZ) && ((b.w - b.y) >= MINSZ))
                    atomicOr(&svalid[rank >> 5], 1u << (rank & 31));
            }
        }
        __syncthreads();
        // transposed matrix slice: gmatT[gr*CA + jcol] bit c = row 64*gr+c suppresses col jcol
        {
            int task = blockIdx.x * 256 + tid;
            int gr = task / CA;
            int jcol = task - gr * CA;
            int j0 = gr << 6;
            u64 bits = 0;
            if (j0 < jcol) {
                float4 b = sroi[jcol];
                float ab = sarea[jcol];
                int cmax = jcol - j0; cmax = cmax > 64 ? 64 : cmax;
                for (int c = 0; c < cmax; ++c) {
                    int row = j0 + c;
                    float4 r = sroi[row];
                    float yy1 = fmaxf(r.x, b.x);
                    float xx1 = fmaxf(r.y, b.y);
                    float yy2 = fminf(r.z, b.z);
                    float xx2 = fminf(r.w, b.w);
                    float inter = fmaxf(yy2 - yy1, 0.0f) * fmaxf(xx2 - xx1, 0.0f);
                    float iou = inter / (sarea[row] + ab - inter);  // ref op order
                    if (iou > NMS_T) bits |= (1ULL << c);
                }
            }
            gmatT[gr * CA + jcol] = bits;
        }
    }
    // arrive-only done counter; last block continues alone
    __threadfence();
    __syncthreads();
    if (tid == 0) {
        unsigned d = atomicAdd(&cnts[6], 1u);
        sIsLast = (d == GRIDR - 1);
    }
    __syncthreads();
    if (!sIsLast) return;
    __threadfence();   // acquire

    // ---- fixed-point NMS: O(#suppressed) rounds; exact (confirmed-prefix argument) ----
    if (tid < 64 && mainValid) {
        u64 M[NG][NG];
#pragma unroll
        for (int gq = 0; gq < NG; ++gq)
#pragma unroll
            for (int g = 0; g < NG; ++g)
                M[gq][g] = gmatT[g * CA + 64 * gq + tid];
        u64 inval[NG];
#pragma unroll
        for (int g = 0; g < NG; ++g)
            inval[g] = ~(((u64)svalid[2 * g + 1] << 32) | (u64)svalid[2 * g]);

        u64 K[NG];
        int nk = 0;
        {
            int run = 0;
#pragma unroll
            for (int g = 0; g < NG; ++g) {
                u64 m = ~inval[g];
                int c = __popcll(m);
                if (run + c <= NPOST) { K[g] = m; run += c; }
                else {
                    int need = NPOST - run;
                    u64 r2 = 0;
                    for (int t = 0; t < need; ++t) { int b = (int)__builtin_ctzll(m); r2 |= 1ull << b; m &= m - 1; }
                    K[g] = r2; run = NPOST;
                }
            }
            nk = run;
        }
        for (int it = 0; it <= CA; ++it) {
            u64 supp[NG];
#pragma unroll
            for (int gq = 0; gq < NG; ++gq) {
                u64 acc = 0;
#pragma unroll
                for (int g = 0; g < NG; ++g) acc |= M[gq][g] & K[g];
                supp[gq] = __ballot(acc != 0ull);
            }
            u64 Kn[NG];
            int run = 0;
#pragma unroll
            for (int g = 0; g < NG; ++g) {
                u64 m = ~supp[g] & ~inval[g];
                int c = __popcll(m);
                if (run + c <= NPOST) { Kn[g] = m; run += c; }
                else {
                    int need = NPOST - run;
                    u64 r2 = 0;
                    for (int t = 0; t < need; ++t) { int b = (int)__builtin_ctzll(m); r2 |= 1ull << b; m &= m - 1; }
                    Kn[g] = r2; run = NPOST;
                }
            }
            bool same = true;
#pragma unroll
            for (int g = 0; g < NG; ++g) same = same && (Kn[g] == K[g]);
#pragma unroll
            for (int g = 0; g < NG; ++g) K[g] = Kn[g];
            nk = run;
            if (same) break;
        }
        if (tid == 0) {
            snk = nk;
            sflag = (nk < NPOST) ? 1 : 0;
#pragma unroll
            for (int g = 0; g < NG; ++g) skm[g] = K[g];
        }
    }
    if (tid == 0 && !mainValid) {
        snk = 0; sflag = 1;
#pragma unroll
        for (int g = 0; g < NG; ++g) skm[g] = 0ull;
    }
    __syncthreads();
    int nk = snk, flag = sflag;
    float4* out4 = (float4*)out;
    if (!flag) {
        int basepc[NG];
        {
            int run = 0;
#pragma unroll
            for (int g = 0; g < NG; ++g) { basepc[g] = run; run += __popcll(skm[g]); }
        }
        int wv = tid >> 6, j = tid & 63;
#pragma unroll
        for (int gg = 0; gg < 2; ++gg) {
            int g = wv + 4 * gg;
            if (g < NG) {
                u64 km = skm[g];
                if ((km >> j) & 1ull) {
                    int rank = basepc[g] + __popcll(km & ((1ull << j) - 1ull));
                    if (rank < NPOST) out4[rank] = sroi[64 * g + j];
                }
            }
        }
        for (int k = nk + tid; k < NPOST; k += 256) out4[k] = make_float4(0.f,0.f,0.f,0.f);
        return;
    }
    // ---------- exact fallback (gated; never taken on sane data) ----------
    __syncthreads();
    for (int b = tid; b < NBIN; b += 256) sm.c.shist[b] = 0;
    __syncthreads();
    for (int i = tid; i < n; i += 256) atomicAdd(&sm.c.shist[sbin_of(score[i])], 1u);
    __syncthreads();
    fastscan2048(sm.c.shist, NPRE, 0, swave, res);
    unsigned b6 = res[0];
    if (tid == 0) sFNW = 0;
    __syncthreads();
    for (int i = tid; i < n; i += 256) {
        float s = score[i];
        if ((unsigned)sbin_of(s) <= b6) {
            float4 r = decode_box(anchor[i], loc[i], ih, iw);
            bool valid = ((r.z - r.x) >= MINSZ) && ((r.w - r.y) >= MINSZ);
            float ms = valid ? s : -__builtin_inff();
            u64 key = ((u64)inv_key(ms) << 32) | (unsigned)i;
            unsigned p = atomicAdd(&sFNW, 1u);
            if (p < CAP6) cand6[p] = key;
        }
    }
    __threadfence();
    __syncthreads();
    unsigned M2 = sFNW < (unsigned)CAP6 ? sFNW : (unsigned)CAP6;
    for (unsigned i = tid; i < CAP6; i += 256) sm.fb.lk[i] = (i < M2) ? cand6[i] : ~0ULL;
    for (int r = tid; r < NPRE; r += 256) order6[r] = 0xFFFFFFFFu;
    __syncthreads();
    for (unsigned c = tid; c < M2; c += 256) {
        u64 key = sm.fb.lk[c];
        int rank = 0;
        for (unsigned j = 0; j < M2; ++j) rank += (sm.fb.lk[j] < key) ? 1 : 0;
        if (rank < NPRE) order6[rank] = (unsigned)key;
    }
    __syncthreads();
    for (int r = tid; r < NPRE; r += 256) {
        unsigned idx = order6[r];
        float4 b = make_float4(0.f, 0.f, 0.f, 0.f);
        if (idx < (unsigned)n) b = decode_box(anchor[idx], loc[idx], ih, iw);
        roi6[r] = b;
    }
    __syncthreads();
    if (tid < 64) {
        int lane = tid;
        int nk2 = 0;
        for (int i = 0; i < NPRE; i++) {
            float4 b = roi6[i];
            float hs = b.z - b.x, wd = b.w - b.y;
            if (!(hs >= MINSZ && wd >= MINSZ)) continue;
            float ab = hs * wd;
            bool sup = false;
            for (int base = 0; base < nk2 && !sup; base += 64) {
                int t = base + lane;
                bool s = false;
                if (t < nk2) {
                    float yy1 = fmaxf(b.x, sm.fb.y1[t]);
                    float xx1 = fmaxf(b.y, sm.fb.x1[t]);
                    float yy2 = fminf(b.z, sm.fb.y2[t]);
                    float xx2 = fminf(b.w, sm.fb.x2[t]);
                    float inter = fmaxf(yy2 - yy1, 0.0f) * fmaxf(xx2 - xx1, 0.0f);
                    float iou = inter / (sm.fb.ar[t] + ab - inter);
                    s = iou > NMS_T;
                }
                sup = (__ballot(s) != 0ULL);
            }
            if (!sup) {
                if (lane == 0) {
                    sm.fb.y1[nk2] = b.x; sm.fb.x1[nk2] = b.y;
                    sm.fb.y2[nk2] = b.z; sm.fb.x2[nk2] = b.w; sm.fb.ar[nk2] = ab;
                }
                nk2++;
                if (nk2 == NPOST) break;
            }
        }
        for (int k = lane; k < NPOST; k += 64) {
            float4 o = make_float4(0.f, 0.f, 0.f, 0.f);
            if (k < nk2) o = make_float4(sm.fb.y1[k], sm.fb.x1[k], sm.fb.y2[k], sm.fb.x2[k]);
            out4[k] = o;
        }
    }
}

extern "C" void kernel_launch(void* const* d_in, const int* in_sizes, int n_in,
                              void* d_out, int out_size, void* d_ws, size_t ws_size,
                              hipStream_t stream) {
    const float4* loc    = (const float4*)d_in[0];
    const float*  score  = (const float*)d_in[1];
    const float4* anchor = (const float4*)d_in[2];
    const int*    ph     = (const int*)d_in[3];
    const int*    pw     = (const int*)d_in[4];
    int n = in_sizes[1];

    char* ws = (char*)d_ws;
    u64*      cand6  = (u64*)(ws + OFF_CAND6);
    u64*      candA  = (u64*)(ws + OFF_CANDA);
    unsigned* candW  = (unsigned*)(ws + OFF_CANDW);
    unsigned* vW     = (unsigned*)(ws + OFF_VW);
    unsigned* order6 = (unsigned*)(ws + OFF_ORDER6);
    float4*   roi6   = (float4*)(ws + OFF_ROI6);
    u64*      gmatT  = (u64*)(ws + OFF_GMAT);
    unsigned* cnts   = (unsigned*)(ws + OFF_CNT);
    float* out = (float*)d_out;

    k_collect <<<dim3(GRIDC), dim3(256), 0, stream>>>(loc, score, anchor, ph, pw, n,
                                                      candA, candW, vW, cnts);
    k_rankmat <<<dim3(GRIDR), dim3(256), 0, stream>>>(loc, score, anchor, ph, pw, n,
                                                      candA, candW, vW, cand6, cnts,
                                                      gmatT, order6, roi6, out);
}